// Round 1
// baseline (3770.898 us; speedup 1.0000x reference)
//
#include <hip/hip_runtime.h>
#include <cstdint>
#include <cstddef>

#define NN 50000
#define NE 500000

__device__ __forceinline__ float relu_f(float v) { return fmaxf(v, 0.0f); }

// ---------------- degree count + reciprocal ----------------
__global__ __launch_bounds__(256) void k_count(const int* __restrict__ dst, float* __restrict__ cnt) {
    int e = blockIdx.x * 256 + threadIdx.x;
    if (e < NE) atomicAdd(&cnt[dst[e]], 1.0f);
}

__global__ __launch_bounds__(256) void k_invcnt(float* __restrict__ cnt) {
    int i = blockIdx.x * 256 + threadIdx.x;
    if (i < NN) cnt[i] = 1.0f / fmaxf(cnt[i], 1.0f);
}

// ---------------- message GEMM + scatter ----------------
// rows = edges (32/block), A = [x[src] (128) | ea (64)], W: 192x128, relu, atomic scatter to agg[dst]
__global__ __launch_bounds__(256) void k_msg(
    const float* __restrict__ x, const float* __restrict__ ea,
    const int* __restrict__ src, const int* __restrict__ dst,
    const float* __restrict__ W, const float* __restrict__ bias,
    float* __restrict__ agg)
{
    constexpr int KC = 64, NP = 3, EB = 32;
    __shared__ __align__(16) float At[KC][EB + 4];
    __shared__ __align__(16) float Wc[KC][128];
    __shared__ int s_src[EB], s_dst[EB];
    const int tid = threadIdx.x;
    const int rowbase = blockIdx.x * EB;
    if (tid < EB) { s_src[tid] = src[rowbase + tid]; s_dst[tid] = dst[rowbase + tid]; }
    __syncthreads();
    const int wave = tid >> 6, lane = tid & 63;
    float acc[16];
#pragma unroll
    for (int i = 0; i < 16; ++i) acc[i] = 0.0f;

    for (int kp = 0; kp < NP; ++kp) {
        const int k0 = kp * KC;
        for (int i = tid; i < KC * EB; i += 256) {
            int e = i >> 6, kk = i & 63, k = k0 + kk;
            float v = (k < 128) ? x[(size_t)s_src[e] * 128 + k]
                                : ea[(size_t)(rowbase + e) * 64 + (k - 128)];
            At[kk][e] = v;
        }
        for (int i = tid; i < KC * 128; i += 256) {
            int kk = i >> 7, cc = i & 127;
            Wc[kk][cc] = W[(size_t)(k0 + kk) * 128 + cc];
        }
        __syncthreads();
#pragma unroll 4
        for (int kk = 0; kk < KC; ++kk) {
            const float* ar = &At[kk][wave * 8];
            float4 a0 = *(const float4*)ar;
            float4 a1 = *(const float4*)(ar + 4);
            float w0 = Wc[kk][lane], w1 = Wc[kk][64 + lane];
            acc[0] += a0.x * w0;  acc[1] += a0.y * w0;  acc[2] += a0.z * w0;  acc[3] += a0.w * w0;
            acc[4] += a1.x * w0;  acc[5] += a1.y * w0;  acc[6] += a1.z * w0;  acc[7] += a1.w * w0;
            acc[8] += a0.x * w1;  acc[9] += a0.y * w1;  acc[10] += a0.z * w1; acc[11] += a0.w * w1;
            acc[12] += a1.x * w1; acc[13] += a1.y * w1; acc[14] += a1.z * w1; acc[15] += a1.w * w1;
        }
        __syncthreads();
    }
    const float b0 = bias[lane], b1 = bias[64 + lane];
#pragma unroll
    for (int j = 0; j < 8; ++j) {
        int e = wave * 8 + j;
        size_t d = (size_t)s_dst[e] * 128;
        atomicAdd(&agg[d + lane],      relu_f(acc[j] + b0));
        atomicAdd(&agg[d + 64 + lane], relu_f(acc[8 + j] + b1));
    }
}

// ---------------- node update GEMM ----------------
// rows = nodes, A = [agg*icnt (128) | xin (128)], W: 256x128, relu, write xout + sum-of-squares
__global__ __launch_bounds__(256) void k_update(
    const float* __restrict__ agg, const float* __restrict__ icnt,
    const float* __restrict__ xin, float* __restrict__ xout,
    const float* __restrict__ W, const float* __restrict__ bias,
    float* __restrict__ ss)
{
    constexpr int KC = 64, NP = 4, EB = 32;
    __shared__ __align__(16) float At[KC][EB + 4];
    __shared__ __align__(16) float Wc[KC][128];
    __shared__ float s_ic[EB];
    const int tid = threadIdx.x;
    const int rowbase = blockIdx.x * EB;
    if (tid < EB) { int r = min(rowbase + tid, NN - 1); s_ic[tid] = icnt[r]; }
    __syncthreads();
    const int wave = tid >> 6, lane = tid & 63;
    float acc[16];
#pragma unroll
    for (int i = 0; i < 16; ++i) acc[i] = 0.0f;

    for (int kp = 0; kp < NP; ++kp) {
        const int k0 = kp * KC;
        for (int i = tid; i < KC * EB; i += 256) {
            int e = i >> 6, kk = i & 63, k = k0 + kk;
            int r = min(rowbase + e, NN - 1);
            float v = (k < 128) ? agg[(size_t)r * 128 + k] * s_ic[e]
                                : xin[(size_t)r * 128 + (k - 128)];
            At[kk][e] = v;
        }
        for (int i = tid; i < KC * 128; i += 256) {
            int kk = i >> 7, cc = i & 127;
            Wc[kk][cc] = W[(size_t)(k0 + kk) * 128 + cc];
        }
        __syncthreads();
#pragma unroll 4
        for (int kk = 0; kk < KC; ++kk) {
            const float* ar = &At[kk][wave * 8];
            float4 a0 = *(const float4*)ar;
            float4 a1 = *(const float4*)(ar + 4);
            float w0 = Wc[kk][lane], w1 = Wc[kk][64 + lane];
            acc[0] += a0.x * w0;  acc[1] += a0.y * w0;  acc[2] += a0.z * w0;  acc[3] += a0.w * w0;
            acc[4] += a1.x * w0;  acc[5] += a1.y * w0;  acc[6] += a1.z * w0;  acc[7] += a1.w * w0;
            acc[8] += a0.x * w1;  acc[9] += a0.y * w1;  acc[10] += a0.z * w1; acc[11] += a0.w * w1;
            acc[12] += a1.x * w1; acc[13] += a1.y * w1; acc[14] += a1.z * w1; acc[15] += a1.w * w1;
        }
        __syncthreads();
    }
    const float b0 = bias[lane], b1 = bias[64 + lane];
#pragma unroll
    for (int j = 0; j < 8; ++j) {
        int r = rowbase + wave * 8 + j;
        if (r < NN) {
            float v0 = relu_f(acc[j] + b0);
            float v1 = relu_f(acc[8 + j] + b1);
            xout[(size_t)r * 128 + lane] = v0;
            xout[(size_t)r * 128 + 64 + lane] = v1;
            float s2 = v0 * v0 + v1 * v1;
#pragma unroll
            for (int off = 32; off > 0; off >>= 1) s2 += __shfl_down(s2, off, 64);
            if (lane == 0) atomicAdd(&ss[r], s2);
        }
    }
}

// ---------------- L2-normalize rows ----------------
__global__ __launch_bounds__(256) void k_norm(float* __restrict__ x, const float* __restrict__ ss) {
    int i = blockIdx.x * 256 + threadIdx.x;   // grid sized exactly NN*128/256
    int r = i >> 7;
    float s = ss[r];
    x[i] *= 1.0f / fmaxf(sqrtf(s), 1e-12f);
}

// ---------------- edge update GEMM ----------------
// rows = edges, A = [x[src] (128) | x[dst] (128) | ein (64)], W: 320x64, relu, write eout
__global__ __launch_bounds__(256) void k_edge(
    const float* __restrict__ x, const float* __restrict__ ein,
    const int* __restrict__ src, const int* __restrict__ dst,
    const float* __restrict__ W, const float* __restrict__ bias,
    float* __restrict__ eout)
{
    constexpr int KC = 80, NP = 4, EB = 32;
    __shared__ __align__(16) float At[KC][EB + 4];
    __shared__ __align__(16) float Wc[KC][64];
    __shared__ int s_src[EB], s_dst[EB];
    const int tid = threadIdx.x;
    const int rowbase = blockIdx.x * EB;
    if (tid < EB) { s_src[tid] = src[rowbase + tid]; s_dst[tid] = dst[rowbase + tid]; }
    __syncthreads();
    const int wave = tid >> 6, lane = tid & 63;
    float acc[8];
#pragma unroll
    for (int i = 0; i < 8; ++i) acc[i] = 0.0f;

    for (int kp = 0; kp < NP; ++kp) {
        const int k0 = kp * KC;
        for (int i = tid; i < KC * EB; i += 256) {
            int e = i / KC, kk = i - e * KC, k = k0 + kk;
            float v;
            if (k < 128)      v = x[(size_t)s_src[e] * 128 + k];
            else if (k < 256) v = x[(size_t)s_dst[e] * 128 + (k - 128)];
            else              v = ein[(size_t)(rowbase + e) * 64 + (k - 256)];
            At[kk][e] = v;
        }
        for (int i = tid; i < KC * 64; i += 256) {
            int kk = i >> 6, cc = i & 63;
            Wc[kk][cc] = W[(size_t)(k0 + kk) * 64 + cc];
        }
        __syncthreads();
#pragma unroll 4
        for (int kk = 0; kk < KC; ++kk) {
            const float* ar = &At[kk][wave * 8];
            float4 a0 = *(const float4*)ar;
            float4 a1 = *(const float4*)(ar + 4);
            float wv = Wc[kk][lane];
            acc[0] += a0.x * wv; acc[1] += a0.y * wv; acc[2] += a0.z * wv; acc[3] += a0.w * wv;
            acc[4] += a1.x * wv; acc[5] += a1.y * wv; acc[6] += a1.z * wv; acc[7] += a1.w * wv;
        }
        __syncthreads();
    }
    const float bv = bias[lane];
#pragma unroll
    for (int j = 0; j < 8; ++j) {
        int e = wave * 8 + j;
        eout[(size_t)(rowbase + e) * 64 + lane] = relu_f(acc[j] + bv);
    }
}

// ---------------- MLP head, layer 1: 128 -> 64, relu ----------------
__global__ __launch_bounds__(256) void k_head1(
    const float* __restrict__ x, const float* __restrict__ W, const float* __restrict__ bias,
    float* __restrict__ h)
{
    constexpr int KC = 64, NP = 2, EB = 32;
    __shared__ __align__(16) float At[KC][EB + 4];
    __shared__ __align__(16) float Wc[KC][64];
    const int tid = threadIdx.x;
    const int rowbase = blockIdx.x * EB;
    const int wave = tid >> 6, lane = tid & 63;
    float acc[8];
#pragma unroll
    for (int i = 0; i < 8; ++i) acc[i] = 0.0f;

    for (int kp = 0; kp < NP; ++kp) {
        const int k0 = kp * KC;
        for (int i = tid; i < KC * EB; i += 256) {
            int e = i >> 6, kk = i & 63, k = k0 + kk;
            int r = min(rowbase + e, NN - 1);
            At[kk][e] = x[(size_t)r * 128 + k];
        }
        for (int i = tid; i < KC * 64; i += 256) {
            int kk = i >> 6, cc = i & 63;
            Wc[kk][cc] = W[(size_t)(k0 + kk) * 64 + cc];
        }
        __syncthreads();
#pragma unroll 4
        for (int kk = 0; kk < KC; ++kk) {
            const float* ar = &At[kk][wave * 8];
            float4 a0 = *(const float4*)ar;
            float4 a1 = *(const float4*)(ar + 4);
            float wv = Wc[kk][lane];
            acc[0] += a0.x * wv; acc[1] += a0.y * wv; acc[2] += a0.z * wv; acc[3] += a0.w * wv;
            acc[4] += a1.x * wv; acc[5] += a1.y * wv; acc[6] += a1.z * wv; acc[7] += a1.w * wv;
        }
        __syncthreads();
    }
    const float bv = bias[lane];
#pragma unroll
    for (int j = 0; j < 8; ++j) {
        int r = rowbase + wave * 8 + j;
        if (r < NN) h[(size_t)r * 64 + lane] = relu_f(acc[j] + bv);
    }
}

// ---------------- MLP head, layer 2: 64 -> 128, no relu ----------------
__global__ __launch_bounds__(256) void k_head2(
    const float* __restrict__ h, const float* __restrict__ W, const float* __restrict__ bias,
    float* __restrict__ out)
{
    constexpr int KC = 64, EB = 32;
    __shared__ __align__(16) float At[KC][EB + 4];
    __shared__ __align__(16) float Wc[KC][128];
    const int tid = threadIdx.x;
    const int rowbase = blockIdx.x * EB;
    const int wave = tid >> 6, lane = tid & 63;
    float acc[16];
#pragma unroll
    for (int i = 0; i < 16; ++i) acc[i] = 0.0f;

    for (int i = tid; i < KC * EB; i += 256) {
        int e = i >> 6, kk = i & 63;
        int r = min(rowbase + e, NN - 1);
        At[kk][e] = h[(size_t)r * 64 + kk];
    }
    for (int i = tid; i < KC * 128; i += 256) {
        int kk = i >> 7, cc = i & 127;
        Wc[kk][cc] = W[(size_t)kk * 128 + cc];
    }
    __syncthreads();
#pragma unroll 4
    for (int kk = 0; kk < KC; ++kk) {
        const float* ar = &At[kk][wave * 8];
        float4 a0 = *(const float4*)ar;
        float4 a1 = *(const float4*)(ar + 4);
        float w0 = Wc[kk][lane], w1 = Wc[kk][64 + lane];
        acc[0] += a0.x * w0;  acc[1] += a0.y * w0;  acc[2] += a0.z * w0;  acc[3] += a0.w * w0;
        acc[4] += a1.x * w0;  acc[5] += a1.y * w0;  acc[6] += a1.z * w0;  acc[7] += a1.w * w0;
        acc[8] += a0.x * w1;  acc[9] += a0.y * w1;  acc[10] += a0.z * w1; acc[11] += a0.w * w1;
        acc[12] += a1.x * w1; acc[13] += a1.y * w1; acc[14] += a1.z * w1; acc[15] += a1.w * w1;
    }
    const float b0 = bias[lane], b1 = bias[64 + lane];
#pragma unroll
    for (int j = 0; j < 8; ++j) {
        int r = rowbase + wave * 8 + j;
        if (r < NN) {
            out[(size_t)r * 128 + lane] = acc[j] + b0;
            out[(size_t)r * 128 + 64 + lane] = acc[8 + j] + b1;
        }
    }
}

// ---------------- host-side launch ----------------
extern "C" void kernel_launch(void* const* d_in, const int* in_sizes, int n_in,
                              void* d_out, int out_size, void* d_ws, size_t ws_size,
                              hipStream_t stream) {
    const float* d_x  = (const float*)d_in[0];
    const float* d_ea = (const float*)d_in[1];
    const int*   d_ei = (const int*)d_in[2];
    const float* Wm   = (const float*)d_in[3];
    const float* bm   = (const float*)d_in[4];
    const float* Wa   = (const float*)d_in[5];
    const float* ba   = (const float*)d_in[6];
    const float* We   = (const float*)d_in[7];
    const float* be   = (const float*)d_in[8];
    const float* W1   = (const float*)d_in[9];
    const float* b1   = (const float*)d_in[10];
    const float* W2   = (const float*)d_in[11];
    const float* b2   = (const float*)d_in[12];
    float* out = (float*)d_out;

    const int* src = d_ei;
    const int* dst = d_ei + NE;

    // workspace layout (floats): total 48.1M floats = 192.4 MB
    float* ws   = (float*)d_ws;
    float* xbuf = ws;                              // NN*128
    float* ebuf = xbuf + (size_t)NN * 128;         // NE*64
    float* agg  = ebuf + (size_t)NE * 64;          // NN*128
    float* cnt  = agg + (size_t)NN * 128;          // NN  (count, then 1/max(cnt,1) in place)
    float* ss   = cnt + NN;                        // NN
    float* hbuf = ss + NN;                         // NN*64

    hipMemsetAsync(cnt, 0, NN * sizeof(float), stream);
    k_count<<<(NE + 255) / 256, 256, 0, stream>>>(dst, cnt);
    k_invcnt<<<(NN + 255) / 256, 256, 0, stream>>>(cnt);

    const float* xin = d_x;
    const float* ein = d_ea;
    for (int l = 0; l < 3; ++l) {
        hipMemsetAsync(agg, 0, (size_t)NN * 128 * sizeof(float), stream);
        hipMemsetAsync(ss, 0, NN * sizeof(float), stream);
        k_msg<<<NE / 32, 256, 0, stream>>>(xin, ein, src, dst,
                                           Wm + (size_t)l * 192 * 128, bm + l * 128, agg);
        k_update<<<(NN + 31) / 32, 256, 0, stream>>>(agg, cnt, xin, xbuf,
                                                     Wa + (size_t)l * 256 * 128, ba + l * 128, ss);
        k_norm<<<(NN * 128) / 256, 256, 0, stream>>>(xbuf, ss);
        k_edge<<<NE / 32, 256, 0, stream>>>(xbuf, ein, src, dst,
                                            We + (size_t)l * 320 * 64, be + l * 64, ebuf);
        xin = xbuf;
        ein = ebuf;
    }
    k_head1<<<(NN + 31) / 32, 256, 0, stream>>>(xbuf, W1, b1, hbuf);
    k_head2<<<(NN + 31) / 32, 256, 0, stream>>>(hbuf, W2, b2, out);
}

// Round 2
// 2938.569 us; speedup vs baseline: 1.2832x; 1.2832x over previous
//
#include <hip/hip_runtime.h>
#include <cstdint>
#include <cstddef>

#define NN 50000
#define NE 500000

typedef unsigned short u16;
typedef __attribute__((ext_vector_type(8))) short bf16x8;
typedef __attribute__((ext_vector_type(4))) float f32x4;

__device__ __forceinline__ float relu_f(float v) { return fmaxf(v, 0.0f); }

__device__ __forceinline__ u16 f2bf(float f) {
    union { float f; unsigned u; } c; c.f = f;
    unsigned u = c.u;
    unsigned r = u + 0x7FFFu + ((u >> 16) & 1u);
    return (u16)(r >> 16);
}
__device__ __forceinline__ float bf2f(u16 h) {
    union { unsigned u; float f; } c; c.u = ((unsigned)h) << 16;
    return c.f;
}

// ---------------- degree count + reciprocal ----------------
__global__ __launch_bounds__(256) void k_count(const int* __restrict__ dst, float* __restrict__ cnt) {
    int e = blockIdx.x * 256 + threadIdx.x;
    if (e < NE) atomicAdd(&cnt[dst[e]], 1.0f);
}

__global__ __launch_bounds__(256) void k_invcnt(float* __restrict__ cnt) {
    int i = blockIdx.x * 256 + threadIdx.x;
    if (i < NN) cnt[i] = 1.0f / fmaxf(cnt[i], 1.0f);
}

// ---------------- fp32 -> split bf16 planes ----------------
__global__ __launch_bounds__(256) void k_split(const float* __restrict__ in,
                                               u16* __restrict__ hi, u16* __restrict__ lo, int n) {
    int i = blockIdx.x * 256 + threadIdx.x;
    if (i < n) {
        float v = in[i];
        u16 h = f2bf(v);
        hi[i] = h;
        lo[i] = f2bf(v - bf2f(h));
    }
}

// ---------------- W[k][n] -> transposed split planes Wt[n][k] ----------------
__global__ __launch_bounds__(256) void k_wt(const float* __restrict__ W,
                                            u16* __restrict__ th, u16* __restrict__ tl,
                                            int K, int N) {
    int i = blockIdx.x * 256 + threadIdx.x;
    if (i < K * N) {
        int n = i / K, k = i - n * K;
        float v = W[(size_t)k * N + n];
        u16 h = f2bf(v);
        th[i] = h;
        tl[i] = f2bf(v - bf2f(h));
    }
}

// ================= message GEMM (MFMA, split bf16) =================
// rows=edges, block tile 128x128, K=192: [x[src](128) | e(64)] ; relu ; atomic scatter to agg
__global__ __launch_bounds__(256) void k_msg_mfma(
    const u16* __restrict__ xh, const u16* __restrict__ xl,
    const u16* __restrict__ eh, const u16* __restrict__ el,
    const int* __restrict__ src, const int* __restrict__ dst,
    const u16* __restrict__ Bth, const u16* __restrict__ Btl,   // [128][192]
    const float* __restrict__ bias, float* __restrict__ agg)
{
    __shared__ u16 Ah[128][40], Al[128][40], Bh[128][40], Bl[128][40];
    __shared__ int s_src[128], s_dst[128];
    const int tid = threadIdx.x;
    const long rowbase = (long)blockIdx.x * 128;
    if (tid < 128) {
        long r = rowbase + tid;
        int rr = (r < NE) ? (int)r : (NE - 1);
        s_src[tid] = src[rr];
        s_dst[tid] = dst[rr];
    }
    __syncthreads();
    const int wave = tid >> 6, lane = tid & 63;
    const int quad = lane >> 4, lrow = lane & 15;
    const int wr = wave >> 1, wc = wave & 1;
    const int arow = tid >> 1, akh = (tid & 1) << 4;

    f32x4 acc[4][4];
#pragma unroll
    for (int r = 0; r < 4; ++r)
#pragma unroll
        for (int c = 0; c < 4; ++c) acc[r][c] = (f32x4){0.f, 0.f, 0.f, 0.f};

    for (int kp = 0; kp < 6; ++kp) {
        const int k0 = kp * 32;
        // stage A (gathered rows, split planes)
        {
            const u16 *ph, *pl;
            if (k0 < 128) {
                long b = (long)s_src[arow] * 128 + (k0 + akh);
                ph = xh + b; pl = xl + b;
            } else {
                long er = rowbase + arow; if (er >= NE) er = NE - 1;
                long b = er * 64 + (k0 - 128 + akh);
                ph = eh + b; pl = el + b;
            }
            *(int4*)&Ah[arow][akh]     = *(const int4*)ph;
            *(int4*)&Ah[arow][akh + 8] = *(const int4*)(ph + 8);
            *(int4*)&Al[arow][akh]     = *(const int4*)pl;
            *(int4*)&Al[arow][akh + 8] = *(const int4*)(pl + 8);
        }
        // stage B from pre-transposed planes
        {
            long b = (long)arow * 192 + k0 + akh;
            *(int4*)&Bh[arow][akh]     = *(const int4*)(Bth + b);
            *(int4*)&Bh[arow][akh + 8] = *(const int4*)(Bth + b + 8);
            *(int4*)&Bl[arow][akh]     = *(const int4*)(Btl + b);
            *(int4*)&Bl[arow][akh + 8] = *(const int4*)(Btl + b + 8);
        }
        __syncthreads();
        bf16x8 ah[4], al[4], bh[4], bl[4];
#pragma unroll
        for (int r = 0; r < 4; ++r) {
            ah[r] = *(const bf16x8*)&Ah[wr * 64 + r * 16 + lrow][quad * 8];
            al[r] = *(const bf16x8*)&Al[wr * 64 + r * 16 + lrow][quad * 8];
        }
#pragma unroll
        for (int c = 0; c < 4; ++c) {
            bh[c] = *(const bf16x8*)&Bh[wc * 64 + c * 16 + lrow][quad * 8];
            bl[c] = *(const bf16x8*)&Bl[wc * 64 + c * 16 + lrow][quad * 8];
        }
#pragma unroll
        for (int r = 0; r < 4; ++r)
#pragma unroll
            for (int c = 0; c < 4; ++c) {
                acc[r][c] = __builtin_amdgcn_mfma_f32_16x16x32_bf16(ah[r], bh[c], acc[r][c], 0, 0, 0);
                acc[r][c] = __builtin_amdgcn_mfma_f32_16x16x32_bf16(ah[r], bl[c], acc[r][c], 0, 0, 0);
                acc[r][c] = __builtin_amdgcn_mfma_f32_16x16x32_bf16(al[r], bh[c], acc[r][c], 0, 0, 0);
            }
        __syncthreads();
    }
    // epilogue: relu + atomic scatter
#pragma unroll
    for (int c = 0; c < 4; ++c) {
        int colg = wc * 64 + c * 16 + lrow;
        float bv = bias[colg];
#pragma unroll
        for (int r = 0; r < 4; ++r)
#pragma unroll
            for (int j = 0; j < 4; ++j) {
                int lrw = wr * 64 + r * 16 + quad * 4 + j;
                long grow = rowbase + lrw;
                if (grow < NE) {
                    float v = relu_f(acc[r][c][j] + bv);
                    atomicAdd(&agg[(long)s_dst[lrw] * 128 + colg], v);
                }
            }
    }
}

// ================= node update GEMM (MFMA, split bf16) =================
// rows=nodes, block 128x128, K=256: [agg*icnt(128) | x(128)]; relu; write x planes (unnormalized) + ss
__global__ __launch_bounds__(256) void k_update_mfma(
    const float* __restrict__ agg, const float* __restrict__ icnt,
    u16* __restrict__ xh, u16* __restrict__ xl,
    const u16* __restrict__ Bth, const u16* __restrict__ Btl,   // [128][256]
    const float* __restrict__ bias, float* __restrict__ ss)
{
    __shared__ u16 Ah[128][40], Al[128][40], Bh[128][40], Bl[128][40];
    __shared__ float s_ic[128];
    const int tid = threadIdx.x;
    const long rowbase = (long)blockIdx.x * 128;
    if (tid < 128) {
        long r = rowbase + tid;
        int rr = (r < NN) ? (int)r : (NN - 1);
        s_ic[tid] = icnt[rr];
    }
    __syncthreads();
    const int wave = tid >> 6, lane = tid & 63;
    const int quad = lane >> 4, lrow = lane & 15;
    const int wr = wave >> 1, wc = wave & 1;
    const int arow = tid >> 1, akh = (tid & 1) << 4;

    f32x4 acc[4][4];
#pragma unroll
    for (int r = 0; r < 4; ++r)
#pragma unroll
        for (int c = 0; c < 4; ++c) acc[r][c] = (f32x4){0.f, 0.f, 0.f, 0.f};

    for (int kp = 0; kp < 8; ++kp) {
        const int k0 = kp * 32;
        if (k0 < 128) {  // agg * icnt, split on the fly
            long r = rowbase + arow; if (r >= NN) r = NN - 1;
            const float* pa = agg + r * 128 + k0 + akh;
            float ic = s_ic[arow];
#pragma unroll
            for (int q = 0; q < 16; q += 4) {
                float4 f = *(const float4*)(pa + q);
                float vv[4] = {f.x, f.y, f.z, f.w};
#pragma unroll
                for (int j = 0; j < 4; ++j) {
                    float v = vv[j] * ic;
                    u16 h = f2bf(v);
                    Ah[arow][akh + q + j] = h;
                    Al[arow][akh + q + j] = f2bf(v - bf2f(h));
                }
            }
        } else {         // x planes
            long r = rowbase + arow; if (r >= NN) r = NN - 1;
            long b = r * 128 + (k0 - 128 + akh);
            *(int4*)&Ah[arow][akh]     = *(const int4*)(xh + b);
            *(int4*)&Ah[arow][akh + 8] = *(const int4*)(xh + b + 8);
            *(int4*)&Al[arow][akh]     = *(const int4*)(xl + b);
            *(int4*)&Al[arow][akh + 8] = *(const int4*)(xl + b + 8);
        }
        {
            long b = (long)arow * 256 + k0 + akh;
            *(int4*)&Bh[arow][akh]     = *(const int4*)(Bth + b);
            *(int4*)&Bh[arow][akh + 8] = *(const int4*)(Bth + b + 8);
            *(int4*)&Bl[arow][akh]     = *(const int4*)(Btl + b);
            *(int4*)&Bl[arow][akh + 8] = *(const int4*)(Btl + b + 8);
        }
        __syncthreads();
        bf16x8 ah[4], al[4], bh[4], bl[4];
#pragma unroll
        for (int r = 0; r < 4; ++r) {
            ah[r] = *(const bf16x8*)&Ah[wr * 64 + r * 16 + lrow][quad * 8];
            al[r] = *(const bf16x8*)&Al[wr * 64 + r * 16 + lrow][quad * 8];
        }
#pragma unroll
        for (int c = 0; c < 4; ++c) {
            bh[c] = *(const bf16x8*)&Bh[wc * 64 + c * 16 + lrow][quad * 8];
            bl[c] = *(const bf16x8*)&Bl[wc * 64 + c * 16 + lrow][quad * 8];
        }
#pragma unroll
        for (int r = 0; r < 4; ++r)
#pragma unroll
            for (int c = 0; c < 4; ++c) {
                acc[r][c] = __builtin_amdgcn_mfma_f32_16x16x32_bf16(ah[r], bh[c], acc[r][c], 0, 0, 0);
                acc[r][c] = __builtin_amdgcn_mfma_f32_16x16x32_bf16(ah[r], bl[c], acc[r][c], 0, 0, 0);
                acc[r][c] = __builtin_amdgcn_mfma_f32_16x16x32_bf16(al[r], bh[c], acc[r][c], 0, 0, 0);
            }
        __syncthreads();
    }
    // epilogue: relu, write unnormalized x planes (in-place: block owns its rows), ss atomics
#pragma unroll
    for (int c = 0; c < 4; ++c) {
        int colg = wc * 64 + c * 16 + lrow;
        float bv = bias[colg];
#pragma unroll
        for (int r = 0; r < 4; ++r)
#pragma unroll
            for (int j = 0; j < 4; ++j) {
                int lrw = wr * 64 + r * 16 + quad * 4 + j;
                long grow = rowbase + lrw;
                if (grow < NN) {
                    float v = relu_f(acc[r][c][j] + bv);
                    long o = grow * 128 + colg;
                    u16 h = f2bf(v);
                    xh[o] = h;
                    xl[o] = f2bf(v - bf2f(h));
                    atomicAdd(&ss[grow], v * v);
                }
            }
    }
}

// ---------------- L2-normalize rows (split planes) ----------------
__global__ __launch_bounds__(256) void k_norm(u16* __restrict__ xh, u16* __restrict__ xl,
                                              const float* __restrict__ ss) {
    int i = blockIdx.x * 256 + threadIdx.x;   // grid = NN*128/256 exactly
    int r = i >> 7;
    float rn = 1.0f / fmaxf(sqrtf(ss[r]), 1e-12f);
    float v = (bf2f(xh[i]) + bf2f(xl[i])) * rn;
    u16 h = f2bf(v);
    xh[i] = h;
    xl[i] = f2bf(v - bf2f(h));
}

// ================= edge update GEMM (MFMA, split bf16) =================
// rows=edges, block 256x64, K=320: [x[src](128) | x[dst](128) | e(64)]; relu; write e planes in-place
__global__ __launch_bounds__(256) void k_edge_mfma(
    const u16* __restrict__ xh, const u16* __restrict__ xl,
    u16* __restrict__ eh, u16* __restrict__ el,
    const int* __restrict__ src, const int* __restrict__ dst,
    const u16* __restrict__ Bth, const u16* __restrict__ Btl,   // [64][320]
    const float* __restrict__ bias)
{
    __shared__ u16 Ah[256][40], Al[256][40];
    __shared__ u16 Bh[64][40], Bl[64][40];
    __shared__ int s_src[256], s_dst[256];
    const int tid = threadIdx.x;
    const long rowbase = (long)blockIdx.x * 256;
    {
        long r = rowbase + tid;
        int rr = (r < NE) ? (int)r : (NE - 1);
        s_src[tid] = src[rr];
        s_dst[tid] = dst[rr];
    }
    __syncthreads();
    const int wave = tid >> 6, lane = tid & 63;
    const int quad = lane >> 4, lrow = lane & 15;

    f32x4 acc[4][4];
#pragma unroll
    for (int r = 0; r < 4; ++r)
#pragma unroll
        for (int c = 0; c < 4; ++c) acc[r][c] = (f32x4){0.f, 0.f, 0.f, 0.f};

    for (int kp = 0; kp < 10; ++kp) {
        const int k0 = kp * 32;
        // stage A: one row per thread, 32 k-elems
        {
            const u16 *ph, *pl;
            if (k0 < 128) {
                long b = (long)s_src[tid] * 128 + k0;
                ph = xh + b; pl = xl + b;
            } else if (k0 < 256) {
                long b = (long)s_dst[tid] * 128 + (k0 - 128);
                ph = xh + b; pl = xl + b;
            } else {
                long er = rowbase + tid; if (er >= NE) er = NE - 1;
                long b = er * 64 + (k0 - 256);
                ph = eh + b; pl = el + b;
            }
#pragma unroll
            for (int q = 0; q < 4; ++q) {
                *(int4*)&Ah[tid][q * 8] = *(const int4*)(ph + q * 8);
                *(int4*)&Al[tid][q * 8] = *(const int4*)(pl + q * 8);
            }
        }
        // stage B: 64 cols x 32 k
        {
            int bcol = tid >> 2, bkq = (tid & 3) << 3;
            long b = (long)bcol * 320 + k0 + bkq;
            *(int4*)&Bh[bcol][bkq] = *(const int4*)(Bth + b);
            *(int4*)&Bl[bcol][bkq] = *(const int4*)(Btl + b);
        }
        __syncthreads();
        bf16x8 ah[4], al[4], bh[4], bl[4];
#pragma unroll
        for (int r = 0; r < 4; ++r) {
            ah[r] = *(const bf16x8*)&Ah[wave * 64 + r * 16 + lrow][quad * 8];
            al[r] = *(const bf16x8*)&Al[wave * 64 + r * 16 + lrow][quad * 8];
        }
#pragma unroll
        for (int c = 0; c < 4; ++c) {
            bh[c] = *(const bf16x8*)&Bh[c * 16 + lrow][quad * 8];
            bl[c] = *(const bf16x8*)&Bl[c * 16 + lrow][quad * 8];
        }
#pragma unroll
        for (int r = 0; r < 4; ++r)
#pragma unroll
            for (int c = 0; c < 4; ++c) {
                acc[r][c] = __builtin_amdgcn_mfma_f32_16x16x32_bf16(ah[r], bh[c], acc[r][c], 0, 0, 0);
                acc[r][c] = __builtin_amdgcn_mfma_f32_16x16x32_bf16(ah[r], bl[c], acc[r][c], 0, 0, 0);
                acc[r][c] = __builtin_amdgcn_mfma_f32_16x16x32_bf16(al[r], bh[c], acc[r][c], 0, 0, 0);
            }
        __syncthreads();
    }
    // epilogue: relu + split-write e planes
#pragma unroll
    for (int c = 0; c < 4; ++c) {
        int colg = c * 16 + lrow;
        float bv = bias[colg];
#pragma unroll
        for (int r = 0; r < 4; ++r)
#pragma unroll
            for (int j = 0; j < 4; ++j) {
                int lrw = wave * 64 + r * 16 + quad * 4 + j;
                long grow = rowbase + lrw;
                if (grow < NE) {
                    float v = relu_f(acc[r][c][j] + bv);
                    long o = grow * 64 + colg;
                    u16 h = f2bf(v);
                    eh[o] = h;
                    el[o] = f2bf(v - bf2f(h));
                }
            }
    }
}

// ---------------- MLP head, layer 1: 128 -> 64, relu (fp32 vector) ----------------
__global__ __launch_bounds__(256) void k_head1(
    const u16* __restrict__ xh, const u16* __restrict__ xl,
    const float* __restrict__ W, const float* __restrict__ bias,
    float* __restrict__ h)
{
    constexpr int KC = 64, NP = 2, EB = 32;
    __shared__ __align__(16) float At[KC][EB + 4];
    __shared__ __align__(16) float Wc[KC][64];
    const int tid = threadIdx.x;
    const int rowbase = blockIdx.x * EB;
    const int wave = tid >> 6, lane = tid & 63;
    float acc[8];
#pragma unroll
    for (int i = 0; i < 8; ++i) acc[i] = 0.0f;

    for (int kp = 0; kp < NP; ++kp) {
        const int k0 = kp * KC;
        for (int i = tid; i < KC * EB; i += 256) {
            int e = i >> 6, kk = i & 63, k = k0 + kk;
            int r = min(rowbase + e, NN - 1);
            long b = (long)r * 128 + k;
            At[kk][e] = bf2f(xh[b]) + bf2f(xl[b]);
        }
        for (int i = tid; i < KC * 64; i += 256) {
            int kk = i >> 6, cc = i & 63;
            Wc[kk][cc] = W[(size_t)(k0 + kk) * 64 + cc];
        }
        __syncthreads();
#pragma unroll 4
        for (int kk = 0; kk < KC; ++kk) {
            const float* ar = &At[kk][wave * 8];
            float4 a0 = *(const float4*)ar;
            float4 a1 = *(const float4*)(ar + 4);
            float wv = Wc[kk][lane];
            acc[0] += a0.x * wv; acc[1] += a0.y * wv; acc[2] += a0.z * wv; acc[3] += a0.w * wv;
            acc[4] += a1.x * wv; acc[5] += a1.y * wv; acc[6] += a1.z * wv; acc[7] += a1.w * wv;
        }
        __syncthreads();
    }
    const float bv = bias[lane];
#pragma unroll
    for (int j = 0; j < 8; ++j) {
        int r = rowbase + wave * 8 + j;
        if (r < NN) h[(size_t)r * 64 + lane] = relu_f(acc[j] + bv);
    }
}

// ---------------- MLP head, layer 2: 64 -> 128, no relu ----------------
__global__ __launch_bounds__(256) void k_head2(
    const float* __restrict__ h, const float* __restrict__ W, const float* __restrict__ bias,
    float* __restrict__ out)
{
    constexpr int KC = 64, EB = 32;
    __shared__ __align__(16) float At[KC][EB + 4];
    __shared__ __align__(16) float Wc[KC][128];
    const int tid = threadIdx.x;
    const int rowbase = blockIdx.x * EB;
    const int wave = tid >> 6, lane = tid & 63;
    float acc[16];
#pragma unroll
    for (int i = 0; i < 16; ++i) acc[i] = 0.0f;

    for (int i = tid; i < KC * EB; i += 256) {
        int e = i >> 6, kk = i & 63;
        int r = min(rowbase + e, NN - 1);
        At[kk][e] = h[(size_t)r * 64 + kk];
    }
    for (int i = tid; i < KC * 128; i += 256) {
        int kk = i >> 7, cc = i & 127;
        Wc[kk][cc] = W[(size_t)kk * 128 + cc];
    }
    __syncthreads();
#pragma unroll 4
    for (int kk = 0; kk < KC; ++kk) {
        const float* ar = &At[kk][wave * 8];
        float4 a0 = *(const float4*)ar;
        float4 a1 = *(const float4*)(ar + 4);
        float w0 = Wc[kk][lane], w1 = Wc[kk][64 + lane];
        acc[0] += a0.x * w0;  acc[1] += a0.y * w0;  acc[2] += a0.z * w0;  acc[3] += a0.w * w0;
        acc[4] += a1.x * w0;  acc[5] += a1.y * w0;  acc[6] += a1.z * w0;  acc[7] += a1.w * w0;
        acc[8] += a0.x * w1;  acc[9] += a0.y * w1;  acc[10] += a0.z * w1; acc[11] += a0.w * w1;
        acc[12] += a1.x * w1; acc[13] += a1.y * w1; acc[14] += a1.z * w1; acc[15] += a1.w * w1;
    }
    const float b0 = bias[lane], b1 = bias[64 + lane];
#pragma unroll
    for (int j = 0; j < 8; ++j) {
        int r = rowbase + wave * 8 + j;
        if (r < NN) {
            out[(size_t)r * 128 + lane] = acc[j] + b0;
            out[(size_t)r * 128 + 64 + lane] = acc[8 + j] + b1;
        }
    }
}

// ---------------- host-side launch ----------------
extern "C" void kernel_launch(void* const* d_in, const int* in_sizes, int n_in,
                              void* d_out, int out_size, void* d_ws, size_t ws_size,
                              hipStream_t stream) {
    const float* d_x  = (const float*)d_in[0];
    const float* d_ea = (const float*)d_in[1];
    const int*   d_ei = (const int*)d_in[2];
    const float* Wm   = (const float*)d_in[3];
    const float* bm   = (const float*)d_in[4];
    const float* Wa   = (const float*)d_in[5];
    const float* ba   = (const float*)d_in[6];
    const float* We   = (const float*)d_in[7];
    const float* be   = (const float*)d_in[8];
    const float* W1   = (const float*)d_in[9];
    const float* b1   = (const float*)d_in[10];
    const float* W2   = (const float*)d_in[11];
    const float* b2   = (const float*)d_in[12];
    float* out = (float*)d_out;

    const int* src = d_ei;
    const int* dst = d_ei + NE;

    // workspace layout (~180 MB)
    char* p = (char*)d_ws;
    auto alloc = [&](size_t bytes) { char* q = p; p += (bytes + 255) & ~(size_t)255; return q; };
    u16* xh = (u16*)alloc((size_t)NN * 128 * 2);
    u16* xl = (u16*)alloc((size_t)NN * 128 * 2);
    u16* ehb = (u16*)alloc((size_t)NE * 64 * 2);
    u16* elb = (u16*)alloc((size_t)NE * 64 * 2);
    float* agg = (float*)alloc((size_t)NN * 128 * 4);
    float* cnt = (float*)alloc((size_t)NN * 4);
    float* ss  = (float*)alloc((size_t)NN * 4);
    u16* Wmt_h = (u16*)alloc((size_t)3 * 192 * 128 * 2);
    u16* Wmt_l = (u16*)alloc((size_t)3 * 192 * 128 * 2);
    u16* Wat_h = (u16*)alloc((size_t)3 * 256 * 128 * 2);
    u16* Wat_l = (u16*)alloc((size_t)3 * 256 * 128 * 2);
    u16* Wet_h = (u16*)alloc((size_t)3 * 320 * 64 * 2);
    u16* Wet_l = (u16*)alloc((size_t)3 * 320 * 64 * 2);
    float* hbuf = agg;   // alias: agg unused after last k_update

    hipMemsetAsync(cnt, 0, NN * sizeof(float), stream);
    k_count<<<(NE + 255) / 256, 256, 0, stream>>>(dst, cnt);
    k_invcnt<<<(NN + 255) / 256, 256, 0, stream>>>(cnt);

    k_split<<<(NN * 128 + 255) / 256, 256, 0, stream>>>(d_x, xh, xl, NN * 128);
    k_split<<<(NE * 64 + 255) / 256, 256, 0, stream>>>(d_ea, ehb, elb, NE * 64);
    for (int l = 0; l < 3; ++l) {
        k_wt<<<(192 * 128 + 255) / 256, 256, 0, stream>>>(Wm + (size_t)l * 192 * 128,
            Wmt_h + (size_t)l * 192 * 128, Wmt_l + (size_t)l * 192 * 128, 192, 128);
        k_wt<<<(256 * 128 + 255) / 256, 256, 0, stream>>>(Wa + (size_t)l * 256 * 128,
            Wat_h + (size_t)l * 256 * 128, Wat_l + (size_t)l * 256 * 128, 256, 128);
        k_wt<<<(320 * 64 + 255) / 256, 256, 0, stream>>>(We + (size_t)l * 320 * 64,
            Wet_h + (size_t)l * 320 * 64, Wet_l + (size_t)l * 320 * 64, 320, 64);
    }

    for (int l = 0; l < 3; ++l) {
        hipMemsetAsync(agg, 0, (size_t)NN * 128 * sizeof(float), stream);
        hipMemsetAsync(ss, 0, NN * sizeof(float), stream);
        k_msg_mfma<<<(NE + 127) / 128, 256, 0, stream>>>(
            xh, xl, ehb, elb, src, dst,
            Wmt_h + (size_t)l * 192 * 128, Wmt_l + (size_t)l * 192 * 128,
            bm + (size_t)l * 128, agg);
        k_update_mfma<<<(NN + 127) / 128, 256, 0, stream>>>(
            agg, cnt, xh, xl,
            Wat_h + (size_t)l * 256 * 128, Wat_l + (size_t)l * 256 * 128,
            ba + (size_t)l * 128, ss);
        k_norm<<<(NN * 128) / 256, 256, 0, stream>>>(xh, xl, ss);
        k_edge_mfma<<<(NE + 255) / 256, 256, 0, stream>>>(
            xh, xl, ehb, elb, src, dst,
            Wet_h + (size_t)l * 320 * 64, Wet_l + (size_t)l * 320 * 64,
            be + (size_t)l * 64);
    }
    k_head1<<<(NN + 31) / 32, 256, 0, stream>>>(xh, xl, W1, b1, hbuf);
    k_head2<<<(NN + 31) / 32, 256, 0, stream>>>(hbuf, W2, b2, out);
}

// Round 3
// 1743.020 us; speedup vs baseline: 2.1634x; 1.6859x over previous
//
#include <hip/hip_runtime.h>
#include <cstdint>
#include <cstddef>

#define NN 50000
#define NE 500000

typedef unsigned short u16;
typedef __attribute__((ext_vector_type(8))) short bf16x8;
typedef __attribute__((ext_vector_type(4))) float f32x4;

__device__ __forceinline__ float relu_f(float v) { return fmaxf(v, 0.0f); }

__device__ __forceinline__ u16 f2bf(float f) {
    union { float f; unsigned u; } c; c.f = f;
    unsigned u = c.u;
    unsigned r = u + 0x7FFFu + ((u >> 16) & 1u);
    return (u16)(r >> 16);
}
__device__ __forceinline__ float bf2f(u16 h) {
    union { unsigned u; float f; } c; c.u = ((unsigned)h) << 16;
    return c.f;
}

// ---------------- degree count + reciprocal ----------------
__global__ __launch_bounds__(256) void k_count(const int* __restrict__ dst, float* __restrict__ cnt) {
    int e = blockIdx.x * 256 + threadIdx.x;
    if (e < NE) atomicAdd(&cnt[dst[e]], 1.0f);
}

__global__ __launch_bounds__(256) void k_invcnt(float* __restrict__ cnt) {
    int i = blockIdx.x * 256 + threadIdx.x;
    if (i < NN) cnt[i] = 1.0f / fmaxf(cnt[i], 1.0f);
}

// ---------------- counting sort of edges by dst ----------------
__global__ __launch_bounds__(256) void k_hist(const int* __restrict__ dst, int* __restrict__ h) {
    int e = blockIdx.x * 256 + threadIdx.x;
    if (e < NE) atomicAdd(&h[dst[e]], 1);
}

// block-level inclusive scan -> exclusive local + block sums
__global__ __launch_bounds__(512) void k_scan1(const int* __restrict__ h,
                                               int* __restrict__ excl, int* __restrict__ bsum) {
    __shared__ int s[512];
    int tid = threadIdx.x;
    int i = blockIdx.x * 512 + tid;
    int v = (i < NN) ? h[i] : 0;
    s[tid] = v;
    __syncthreads();
    for (int off = 1; off < 512; off <<= 1) {
        int t = (tid >= off) ? s[tid - off] : 0;
        __syncthreads();
        s[tid] += t;
        __syncthreads();
    }
    if (i < NN) excl[i] = s[tid] - v;
    if (tid == 511) bsum[blockIdx.x] = s[511];
}

// single block: exclusive scan of block sums (NB <= 128)
__global__ __launch_bounds__(128) void k_scan2(int* __restrict__ bsum, int nb) {
    __shared__ int s[128];
    int tid = threadIdx.x;
    int v = (tid < nb) ? bsum[tid] : 0;
    s[tid] = v;
    __syncthreads();
    for (int off = 1; off < 128; off <<= 1) {
        int t = (tid >= off) ? s[tid - off] : 0;
        __syncthreads();
        s[tid] += t;
        __syncthreads();
    }
    if (tid < nb) bsum[tid] = s[tid] - v;
}

__global__ __launch_bounds__(512) void k_scan3(const int* __restrict__ excl, const int* __restrict__ bsum,
                                               int* __restrict__ cursor) {
    int i = blockIdx.x * 512 + threadIdx.x;
    if (i < NN) cursor[i] = excl[i] + bsum[blockIdx.x];
}

__global__ __launch_bounds__(256) void k_scatter(const int* __restrict__ dst,
                                                 int* __restrict__ cursor, int* __restrict__ perm) {
    int e = blockIdx.x * 256 + threadIdx.x;
    if (e < NE) {
        int pos = atomicAdd(&cursor[dst[e]], 1);
        perm[pos] = e;
    }
}

// ---------------- fp32 -> split bf16 planes ----------------
__global__ __launch_bounds__(256) void k_split(const float* __restrict__ in,
                                               u16* __restrict__ hi, u16* __restrict__ lo, int n) {
    int i = blockIdx.x * 256 + threadIdx.x;
    if (i < n) {
        float v = in[i];
        u16 h = f2bf(v);
        hi[i] = h;
        lo[i] = f2bf(v - bf2f(h));
    }
}

// ---------------- W[k][n] -> transposed split planes Wt[n][k] ----------------
__global__ __launch_bounds__(256) void k_wt(const float* __restrict__ W,
                                            u16* __restrict__ th, u16* __restrict__ tl,
                                            int K, int N) {
    int i = blockIdx.x * 256 + threadIdx.x;
    if (i < K * N) {
        int n = i / K, k = i - n * K;
        float v = W[(size_t)k * N + n];
        u16 h = f2bf(v);
        th[i] = h;
        tl[i] = f2bf(v - bf2f(h));
    }
}

// ================= message GEMM (MFMA, split bf16, dst-sorted edges) =================
// rows = permuted edges, block tile 128x128, K=192: [x[src](128) | e(64)]; relu;
// LDS run-scan over dst-runs, coalesced atomicAdd per run into agg.
__global__ __launch_bounds__(256) void k_msg_mfma(
    const u16* __restrict__ xh, const u16* __restrict__ xl,
    const u16* __restrict__ eh, const u16* __restrict__ el,
    const int* __restrict__ src, const int* __restrict__ dst,
    const int* __restrict__ perm,
    const u16* __restrict__ Bth, const u16* __restrict__ Btl,   // [128][192]
    const float* __restrict__ bias, float* __restrict__ agg)
{
    __shared__ union {
        struct { u16 Ah[128][40]; u16 Al[128][40]; u16 Bh[128][40]; u16 Bl[128][40]; } ab; // 40960 B
        float cbuf[128][66];                                                               // 33792 B
    } u;
    __shared__ int s_src[128], s_dstv[128], s_eid[128];
    const int tid = threadIdx.x;
    const long rowbase = (long)blockIdx.x * 128;
    if (tid < 128) {
        long r = rowbase + tid;
        if (r < NE) {
            int pe = perm[r];
            s_src[tid] = src[pe];
            s_dstv[tid] = dst[pe];
            s_eid[tid] = pe;
        } else {
            s_src[tid] = 0; s_dstv[tid] = -1; s_eid[tid] = 0;
        }
    }
    __syncthreads();
    const int wave = tid >> 6, lane = tid & 63;
    const int quad = lane >> 4, lrow = lane & 15;
    const int wr = wave >> 1, wc = wave & 1;
    const int arow = tid >> 1, akh = (tid & 1) << 4;

    f32x4 acc[4][4];
#pragma unroll
    for (int r = 0; r < 4; ++r)
#pragma unroll
        for (int c = 0; c < 4; ++c) acc[r][c] = (f32x4){0.f, 0.f, 0.f, 0.f};

    for (int kp = 0; kp < 6; ++kp) {
        const int k0 = kp * 32;
        {
            const u16 *ph, *pl;
            if (k0 < 128) {
                long b = (long)s_src[arow] * 128 + (k0 + akh);
                ph = xh + b; pl = xl + b;
            } else {
                long b = (long)s_eid[arow] * 64 + (k0 - 128 + akh);
                ph = eh + b; pl = el + b;
            }
            *(int4*)&u.ab.Ah[arow][akh]     = *(const int4*)ph;
            *(int4*)&u.ab.Ah[arow][akh + 8] = *(const int4*)(ph + 8);
            *(int4*)&u.ab.Al[arow][akh]     = *(const int4*)pl;
            *(int4*)&u.ab.Al[arow][akh + 8] = *(const int4*)(pl + 8);
        }
        {
            long b = (long)arow * 192 + k0 + akh;
            *(int4*)&u.ab.Bh[arow][akh]     = *(const int4*)(Bth + b);
            *(int4*)&u.ab.Bh[arow][akh + 8] = *(const int4*)(Bth + b + 8);
            *(int4*)&u.ab.Bl[arow][akh]     = *(const int4*)(Btl + b);
            *(int4*)&u.ab.Bl[arow][akh + 8] = *(const int4*)(Btl + b + 8);
        }
        __syncthreads();
        bf16x8 ah[4], al[4], bh[4], bl[4];
#pragma unroll
        for (int r = 0; r < 4; ++r) {
            ah[r] = *(const bf16x8*)&u.ab.Ah[wr * 64 + r * 16 + lrow][quad * 8];
            al[r] = *(const bf16x8*)&u.ab.Al[wr * 64 + r * 16 + lrow][quad * 8];
        }
#pragma unroll
        for (int c = 0; c < 4; ++c) {
            bh[c] = *(const bf16x8*)&u.ab.Bh[wc * 64 + c * 16 + lrow][quad * 8];
            bl[c] = *(const bf16x8*)&u.ab.Bl[wc * 64 + c * 16 + lrow][quad * 8];
        }
#pragma unroll
        for (int r = 0; r < 4; ++r)
#pragma unroll
            for (int c = 0; c < 4; ++c) {
                acc[r][c] = __builtin_amdgcn_mfma_f32_16x16x32_bf16(ah[r], bh[c], acc[r][c], 0, 0, 0);
                acc[r][c] = __builtin_amdgcn_mfma_f32_16x16x32_bf16(ah[r], bl[c], acc[r][c], 0, 0, 0);
                acc[r][c] = __builtin_amdgcn_mfma_f32_16x16x32_bf16(al[r], bh[c], acc[r][c], 0, 0, 0);
            }
        __syncthreads();
    }
    // epilogue: two column-half passes through LDS, run-scan + coalesced atomic flush
    const int col = tid & 63, seg = tid >> 6;   // one wave == one 32-row segment
    for (int p = 0; p < 2; ++p) {
        if (wc == p) {
#pragma unroll
            for (int c = 0; c < 4; ++c) {
                float bv = bias[p * 64 + c * 16 + lrow];
#pragma unroll
                for (int r = 0; r < 4; ++r)
#pragma unroll
                    for (int j = 0; j < 4; ++j)
                        u.cbuf[wr * 64 + r * 16 + quad * 4 + j][c * 16 + lrow] =
                            relu_f(acc[r][c][j] + bv);
            }
        }
        __syncthreads();
        int cur = -1; float sum = 0.0f;
        for (int rr = seg * 32; rr < seg * 32 + 32; ++rr) {
            int d = s_dstv[rr];
            if (d != cur) {
                if (cur >= 0) atomicAdd(&agg[(long)cur * 128 + p * 64 + col], sum);
                cur = d; sum = 0.0f;
            }
            sum += u.cbuf[rr][col];
        }
        if (cur >= 0) atomicAdd(&agg[(long)cur * 128 + p * 64 + col], sum);
        __syncthreads();
    }
}

// ================= node update GEMM (MFMA, split bf16, fused L2-norm) =================
// rows=nodes, block 128x128, K=256: [agg*icnt(128) | x(128)]; relu; L2-normalize; write x planes
__global__ __launch_bounds__(256) void k_update_mfma(
    const float* __restrict__ agg, const float* __restrict__ icnt,
    u16* __restrict__ xh, u16* __restrict__ xl,
    const u16* __restrict__ Bth, const u16* __restrict__ Btl,   // [128][256]
    const float* __restrict__ bias)
{
    __shared__ u16 Ah[128][40], Al[128][40], Bh[128][40], Bl[128][40];
    __shared__ float s_ic[128];
    __shared__ float sP[128][2];
    const int tid = threadIdx.x;
    const long rowbase = (long)blockIdx.x * 128;
    if (tid < 128) {
        long r = rowbase + tid;
        int rr = (r < NN) ? (int)r : (NN - 1);
        s_ic[tid] = icnt[rr];
    }
    __syncthreads();
    const int wave = tid >> 6, lane = tid & 63;
    const int quad = lane >> 4, lrow = lane & 15;
    const int wr = wave >> 1, wc = wave & 1;
    const int arow = tid >> 1, akh = (tid & 1) << 4;

    f32x4 acc[4][4];
#pragma unroll
    for (int r = 0; r < 4; ++r)
#pragma unroll
        for (int c = 0; c < 4; ++c) acc[r][c] = (f32x4){0.f, 0.f, 0.f, 0.f};

    for (int kp = 0; kp < 8; ++kp) {
        const int k0 = kp * 32;
        if (k0 < 128) {  // agg * icnt, split on the fly
            long r = rowbase + arow; if (r >= NN) r = NN - 1;
            const float* pa = agg + r * 128 + k0 + akh;
            float ic = s_ic[arow];
#pragma unroll
            for (int q = 0; q < 16; q += 4) {
                float4 f = *(const float4*)(pa + q);
                float vv[4] = {f.x, f.y, f.z, f.w};
#pragma unroll
                for (int j = 0; j < 4; ++j) {
                    float v = vv[j] * ic;
                    u16 h = f2bf(v);
                    Ah[arow][akh + q + j] = h;
                    Al[arow][akh + q + j] = f2bf(v - bf2f(h));
                }
            }
        } else {         // x planes
            long r = rowbase + arow; if (r >= NN) r = NN - 1;
            long b = r * 128 + (k0 - 128 + akh);
            *(int4*)&Ah[arow][akh]     = *(const int4*)(xh + b);
            *(int4*)&Ah[arow][akh + 8] = *(const int4*)(xh + b + 8);
            *(int4*)&Al[arow][akh]     = *(const int4*)(xl + b);
            *(int4*)&Al[arow][akh + 8] = *(const int4*)(xl + b + 8);
        }
        {
            long b = (long)arow * 256 + k0 + akh;
            *(int4*)&Bh[arow][akh]     = *(const int4*)(Bth + b);
            *(int4*)&Bh[arow][akh + 8] = *(const int4*)(Bth + b + 8);
            *(int4*)&Bl[arow][akh]     = *(const int4*)(Btl + b);
            *(int4*)&Bl[arow][akh + 8] = *(const int4*)(Btl + b + 8);
        }
        __syncthreads();
        bf16x8 ah[4], al[4], bh[4], bl[4];
#pragma unroll
        for (int r = 0; r < 4; ++r) {
            ah[r] = *(const bf16x8*)&Ah[wr * 64 + r * 16 + lrow][quad * 8];
            al[r] = *(const bf16x8*)&Al[wr * 64 + r * 16 + lrow][quad * 8];
        }
#pragma unroll
        for (int c = 0; c < 4; ++c) {
            bh[c] = *(const bf16x8*)&Bh[wc * 64 + c * 16 + lrow][quad * 8];
            bl[c] = *(const bf16x8*)&Bl[wc * 64 + c * 16 + lrow][quad * 8];
        }
#pragma unroll
        for (int r = 0; r < 4; ++r)
#pragma unroll
            for (int c = 0; c < 4; ++c) {
                acc[r][c] = __builtin_amdgcn_mfma_f32_16x16x32_bf16(ah[r], bh[c], acc[r][c], 0, 0, 0);
                acc[r][c] = __builtin_amdgcn_mfma_f32_16x16x32_bf16(ah[r], bl[c], acc[r][c], 0, 0, 0);
                acc[r][c] = __builtin_amdgcn_mfma_f32_16x16x32_bf16(al[r], bh[c], acc[r][c], 0, 0, 0);
            }
        __syncthreads();
    }
    // epilogue: relu -> row sum-of-squares (shfl + LDS halves exchange) -> normalize -> write planes
#pragma unroll
    for (int r = 0; r < 4; ++r)
#pragma unroll
        for (int c = 0; c < 4; ++c)
#pragma unroll
            for (int j = 0; j < 4; ++j)
                acc[r][c][j] = relu_f(acc[r][c][j] + bias[wc * 64 + c * 16 + lrow]);
#pragma unroll
    for (int r = 0; r < 4; ++r)
#pragma unroll
        for (int j = 0; j < 4; ++j) {
            float s2 = 0.0f;
#pragma unroll
            for (int c = 0; c < 4; ++c) { float v = acc[r][c][j]; s2 += v * v; }
#pragma unroll
            for (int m = 1; m < 16; m <<= 1) s2 += __shfl_xor(s2, m, 64);
            if (lrow == 0) sP[wr * 64 + r * 16 + quad * 4 + j][wc] = s2;
        }
    __syncthreads();
#pragma unroll
    for (int r = 0; r < 4; ++r)
#pragma unroll
        for (int j = 0; j < 4; ++j) {
            int lr = wr * 64 + r * 16 + quad * 4 + j;
            long grow = rowbase + lr;
            if (grow < NN) {
                float tot = sP[lr][0] + sP[lr][1];
                float rn = 1.0f / fmaxf(sqrtf(tot), 1e-12f);
#pragma unroll
                for (int c = 0; c < 4; ++c) {
                    float v = acc[r][c][j] * rn;
                    long o = grow * 128 + wc * 64 + c * 16 + lrow;
                    u16 h = f2bf(v);
                    xh[o] = h;
                    xl[o] = f2bf(v - bf2f(h));
                }
            }
        }
}

// ================= edge update GEMM (MFMA, split bf16) =================
// rows=edges, block 256x64, K=320: [x[src](128) | x[dst](128) | e(64)]; relu; write e planes in-place
__global__ __launch_bounds__(256) void k_edge_mfma(
    const u16* __restrict__ xh, const u16* __restrict__ xl,
    u16* __restrict__ eh, u16* __restrict__ el,
    const int* __restrict__ src, const int* __restrict__ dst,
    const u16* __restrict__ Bth, const u16* __restrict__ Btl,   // [64][320]
    const float* __restrict__ bias)
{
    __shared__ u16 Ah[256][40], Al[256][40];
    __shared__ u16 Bh[64][40], Bl[64][40];
    __shared__ int s_src[256], s_dst[256];
    const int tid = threadIdx.x;
    const long rowbase = (long)blockIdx.x * 256;
    {
        long r = rowbase + tid;
        int rr = (r < NE) ? (int)r : (NE - 1);
        s_src[tid] = src[rr];
        s_dst[tid] = dst[rr];
    }
    __syncthreads();
    const int wave = tid >> 6, lane = tid & 63;
    const int quad = lane >> 4, lrow = lane & 15;

    f32x4 acc[4][4];
#pragma unroll
    for (int r = 0; r < 4; ++r)
#pragma unroll
        for (int c = 0; c < 4; ++c) acc[r][c] = (f32x4){0.f, 0.f, 0.f, 0.f};

    for (int kp = 0; kp < 10; ++kp) {
        const int k0 = kp * 32;
        {
            const u16 *ph, *pl;
            if (k0 < 128) {
                long b = (long)s_src[tid] * 128 + k0;
                ph = xh + b; pl = xl + b;
            } else if (k0 < 256) {
                long b = (long)s_dst[tid] * 128 + (k0 - 128);
                ph = xh + b; pl = xl + b;
            } else {
                long er = rowbase + tid; if (er >= NE) er = NE - 1;
                long b = er * 64 + (k0 - 256);
                ph = eh + b; pl = el + b;
            }
#pragma unroll
            for (int q = 0; q < 4; ++q) {
                *(int4*)&Ah[tid][q * 8] = *(const int4*)(ph + q * 8);
                *(int4*)&Al[tid][q * 8] = *(const int4*)(pl + q * 8);
            }
        }
        {
            int bcol = tid >> 2, bkq = (tid & 3) << 3;
            long b = (long)bcol * 320 + k0 + bkq;
            *(int4*)&Bh[bcol][bkq] = *(const int4*)(Bth + b);
            *(int4*)&Bl[bcol][bkq] = *(const int4*)(Btl + b);
        }
        __syncthreads();
        bf16x8 ah[4], al[4], bh[4], bl[4];
#pragma unroll
        for (int r = 0; r < 4; ++r) {
            ah[r] = *(const bf16x8*)&Ah[wave * 64 + r * 16 + lrow][quad * 8];
            al[r] = *(const bf16x8*)&Al[wave * 64 + r * 16 + lrow][quad * 8];
        }
#pragma unroll
        for (int c = 0; c < 4; ++c) {
            bh[c] = *(const bf16x8*)&Bh[c * 16 + lrow][quad * 8];
            bl[c] = *(const bf16x8*)&Bl[c * 16 + lrow][quad * 8];
        }
#pragma unroll
        for (int r = 0; r < 4; ++r)
#pragma unroll
            for (int c = 0; c < 4; ++c) {
                acc[r][c] = __builtin_amdgcn_mfma_f32_16x16x32_bf16(ah[r], bh[c], acc[r][c], 0, 0, 0);
                acc[r][c] = __builtin_amdgcn_mfma_f32_16x16x32_bf16(ah[r], bl[c], acc[r][c], 0, 0, 0);
                acc[r][c] = __builtin_amdgcn_mfma_f32_16x16x32_bf16(al[r], bh[c], acc[r][c], 0, 0, 0);
            }
        __syncthreads();
    }
#pragma unroll
    for (int c = 0; c < 4; ++c) {
        int colg = c * 16 + lrow;
        float bv = bias[colg];
#pragma unroll
        for (int r = 0; r < 4; ++r)
#pragma unroll
            for (int j = 0; j < 4; ++j) {
                int lrw = wave * 64 + r * 16 + quad * 4 + j;
                long grow = rowbase + lrw;
                if (grow < NE) {
                    float v = relu_f(acc[r][c][j] + bv);
                    long o = grow * 64 + colg;
                    u16 h = f2bf(v);
                    eh[o] = h;
                    el[o] = f2bf(v - bf2f(h));
                }
            }
    }
}

// ---------------- MLP head, layer 1: 128 -> 64, relu ----------------
__global__ __launch_bounds__(256) void k_head1(
    const u16* __restrict__ xh, const u16* __restrict__ xl,
    const float* __restrict__ W, const float* __restrict__ bias,
    float* __restrict__ h)
{
    constexpr int KC = 64, NP = 2, EB = 32;
    __shared__ __align__(16) float At[KC][EB + 4];
    __shared__ __align__(16) float Wc[KC][64];
    const int tid = threadIdx.x;
    const int rowbase = blockIdx.x * EB;
    const int wave = tid >> 6, lane = tid & 63;
    float acc[8];
#pragma unroll
    for (int i = 0; i < 8; ++i) acc[i] = 0.0f;

    for (int kp = 0; kp < NP; ++kp) {
        const int k0 = kp * KC;
        for (int i = tid; i < KC * EB; i += 256) {
            int e = i >> 6, kk = i & 63, k = k0 + kk;
            int r = min(rowbase + e, NN - 1);
            long b = (long)r * 128 + k;
            At[kk][e] = bf2f(xh[b]) + bf2f(xl[b]);
        }
        for (int i = tid; i < KC * 64; i += 256) {
            int kk = i >> 6, cc = i & 63;
            Wc[kk][cc] = W[(size_t)(k0 + kk) * 64 + cc];
        }
        __syncthreads();
#pragma unroll 4
        for (int kk = 0; kk < KC; ++kk) {
            const float* ar = &At[kk][wave * 8];
            float4 a0 = *(const float4*)ar;
            float4 a1 = *(const float4*)(ar + 4);
            float wv = Wc[kk][lane];
            acc[0] += a0.x * wv; acc[1] += a0.y * wv; acc[2] += a0.z * wv; acc[3] += a0.w * wv;
            acc[4] += a1.x * wv; acc[5] += a1.y * wv; acc[6] += a1.z * wv; acc[7] += a1.w * wv;
        }
        __syncthreads();
    }
    const float bv = bias[lane];
#pragma unroll
    for (int j = 0; j < 8; ++j) {
        int r = rowbase + wave * 8 + j;
        if (r < NN) h[(size_t)r * 64 + lane] = relu_f(acc[j] + bv);
    }
}

// ---------------- MLP head, layer 2: 64 -> 128, no relu ----------------
__global__ __launch_bounds__(256) void k_head2(
    const float* __restrict__ h, const float* __restrict__ W, const float* __restrict__ bias,
    float* __restrict__ out)
{
    constexpr int KC = 64, EB = 32;
    __shared__ __align__(16) float At[KC][EB + 4];
    __shared__ __align__(16) float Wc[KC][128];
    const int tid = threadIdx.x;
    const int rowbase = blockIdx.x * EB;
    const int wave = tid >> 6, lane = tid & 63;
    float acc[16];
#pragma unroll
    for (int i = 0; i < 16; ++i) acc[i] = 0.0f;

    for (int i = tid; i < KC * EB; i += 256) {
        int e = i >> 6, kk = i & 63;
        int r = min(rowbase + e, NN - 1);
        At[kk][e] = h[(size_t)r * 64 + kk];
    }
    for (int i = tid; i < KC * 128; i += 256) {
        int kk = i >> 7, cc = i & 127;
        Wc[kk][cc] = W[(size_t)kk * 128 + cc];
    }
    __syncthreads();
#pragma unroll 4
    for (int kk = 0; kk < KC; ++kk) {
        const float* ar = &At[kk][wave * 8];
        float4 a0 = *(const float4*)ar;
        float4 a1 = *(const float4*)(ar + 4);
        float w0 = Wc[kk][lane], w1 = Wc[kk][64 + lane];
        acc[0] += a0.x * w0;  acc[1] += a0.y * w0;  acc[2] += a0.z * w0;  acc[3] += a0.w * w0;
        acc[4] += a1.x * w0;  acc[5] += a1.y * w0;  acc[6] += a1.z * w0;  acc[7] += a1.w * w0;
        acc[8] += a0.x * w1;  acc[9] += a0.y * w1;  acc[10] += a0.z * w1; acc[11] += a0.w * w1;
        acc[12] += a1.x * w1; acc[13] += a1.y * w1; acc[14] += a1.z * w1; acc[15] += a1.w * w1;
    }
    const float b0 = bias[lane], b1 = bias[64 + lane];
#pragma unroll
    for (int j = 0; j < 8; ++j) {
        int r = rowbase + wave * 8 + j;
        if (r < NN) {
            out[(size_t)r * 128 + lane] = acc[j] + b0;
            out[(size_t)r * 128 + 64 + lane] = acc[8 + j] + b1;
        }
    }
}

// ---------------- host-side launch ----------------
extern "C" void kernel_launch(void* const* d_in, const int* in_sizes, int n_in,
                              void* d_out, int out_size, void* d_ws, size_t ws_size,
                              hipStream_t stream) {
    const float* d_x  = (const float*)d_in[0];
    const float* d_ea = (const float*)d_in[1];
    const int*   d_ei = (const int*)d_in[2];
    const float* Wm   = (const float*)d_in[3];
    const float* bm   = (const float*)d_in[4];
    const float* Wa   = (const float*)d_in[5];
    const float* ba   = (const float*)d_in[6];
    const float* We   = (const float*)d_in[7];
    const float* be   = (const float*)d_in[8];
    const float* W1   = (const float*)d_in[9];
    const float* b1   = (const float*)d_in[10];
    const float* W2   = (const float*)d_in[11];
    const float* b2   = (const float*)d_in[12];
    float* out = (float*)d_out;

    const int* src = d_ei;
    const int* dst = d_ei + NE;

    char* p = (char*)d_ws;
    auto alloc = [&](size_t bytes) { char* q = p; p += (bytes + 255) & ~(size_t)255; return q; };
    u16* xh = (u16*)alloc((size_t)NN * 128 * 2);
    u16* xl = (u16*)alloc((size_t)NN * 128 * 2);
    u16* ehb = (u16*)alloc((size_t)NE * 64 * 2);
    u16* elb = (u16*)alloc((size_t)NE * 64 * 2);
    float* agg = (float*)alloc((size_t)NN * 128 * 4);
    float* cnt = (float*)alloc((size_t)NN * 4);
    u16* Wmt_h = (u16*)alloc((size_t)3 * 192 * 128 * 2);
    u16* Wmt_l = (u16*)alloc((size_t)3 * 192 * 128 * 2);
    u16* Wat_h = (u16*)alloc((size_t)3 * 256 * 128 * 2);
    u16* Wat_l = (u16*)alloc((size_t)3 * 256 * 128 * 2);
    u16* Wet_h = (u16*)alloc((size_t)3 * 320 * 64 * 2);
    u16* Wet_l = (u16*)alloc((size_t)3 * 320 * 64 * 2);
    int* hist   = (int*)alloc((size_t)NN * 4);
    int* excl   = (int*)alloc((size_t)NN * 4);
    int* bsum   = (int*)alloc(128 * 4);
    int* cursor = (int*)alloc((size_t)NN * 4);
    int* perm   = (int*)alloc((size_t)NE * 4);
    float* hbuf = agg;   // alias: agg unused after last k_update

    const int NB1 = (NN + 511) / 512;  // 98

    hipMemsetAsync(cnt, 0, NN * sizeof(float), stream);
    hipMemsetAsync(hist, 0, NN * sizeof(int), stream);
    k_count<<<(NE + 255) / 256, 256, 0, stream>>>(dst, cnt);
    k_invcnt<<<(NN + 255) / 256, 256, 0, stream>>>(cnt);

    // counting sort of edges by dst (once; reused by all 3 layers)
    k_hist<<<(NE + 255) / 256, 256, 0, stream>>>(dst, hist);
    k_scan1<<<NB1, 512, 0, stream>>>(hist, excl, bsum);
    k_scan2<<<1, 128, 0, stream>>>(bsum, NB1);
    k_scan3<<<NB1, 512, 0, stream>>>(excl, bsum, cursor);
    k_scatter<<<(NE + 255) / 256, 256, 0, stream>>>(dst, cursor, perm);

    k_split<<<(NN * 128 + 255) / 256, 256, 0, stream>>>(d_x, xh, xl, NN * 128);
    k_split<<<(NE * 64 + 255) / 256, 256, 0, stream>>>(d_ea, ehb, elb, NE * 64);
    for (int l = 0; l < 3; ++l) {
        k_wt<<<(192 * 128 + 255) / 256, 256, 0, stream>>>(Wm + (size_t)l * 192 * 128,
            Wmt_h + (size_t)l * 192 * 128, Wmt_l + (size_t)l * 192 * 128, 192, 128);
        k_wt<<<(256 * 128 + 255) / 256, 256, 0, stream>>>(Wa + (size_t)l * 256 * 128,
            Wat_h + (size_t)l * 256 * 128, Wat_l + (size_t)l * 256 * 128, 256, 128);
        k_wt<<<(320 * 64 + 255) / 256, 256, 0, stream>>>(We + (size_t)l * 320 * 64,
            Wet_h + (size_t)l * 320 * 64, Wet_l + (size_t)l * 320 * 64, 320, 64);
    }

    for (int l = 0; l < 3; ++l) {
        hipMemsetAsync(agg, 0, (size_t)NN * 128 * sizeof(float), stream);
        k_msg_mfma<<<(NE + 127) / 128, 256, 0, stream>>>(
            xh, xl, ehb, elb, src, dst, perm,
            Wmt_h + (size_t)l * 192 * 128, Wmt_l + (size_t)l * 192 * 128,
            bm + (size_t)l * 128, agg);
        k_update_mfma<<<(NN + 127) / 128, 256, 0, stream>>>(
            agg, cnt, xh, xl,
            Wat_h + (size_t)l * 256 * 128, Wat_l + (size_t)l * 256 * 128,
            ba + (size_t)l * 128);
        k_edge_mfma<<<(NE + 255) / 256, 256, 0, stream>>>(
            xh, xl, ehb, elb, src, dst,
            Wet_h + (size_t)l * 320 * 64, Wet_l + (size_t)l * 320 * 64,
            be + (size_t)l * 64);
    }
    k_head1<<<(NN + 31) / 32, 256, 0, stream>>>(xh, xl, W1, b1, hbuf);
    k_head2<<<(NN + 31) / 32, 256, 0, stream>>>(hbuf, W2, b2, out);
}

// Round 4
// 1395.931 us; speedup vs baseline: 2.7014x; 1.2486x over previous
//
#include <hip/hip_runtime.h>
#include <cstdint>
#include <cstddef>

#define NN 50000
#define NE 500000

typedef unsigned short u16;
typedef __attribute__((ext_vector_type(8))) short bf16x8;
typedef __attribute__((ext_vector_type(4))) float f32x4;

__device__ __forceinline__ float relu_f(float v) { return fmaxf(v, 0.0f); }

__device__ __forceinline__ u16 f2bf(float f) {
    union { float f; unsigned u; } c; c.f = f;
    unsigned u = c.u;
    unsigned r = u + 0x7FFFu + ((u >> 16) & 1u);
    return (u16)(r >> 16);
}
__device__ __forceinline__ float bf2f(u16 h) {
    union { unsigned u; float f; } c; c.u = ((unsigned)h) << 16;
    return c.f;
}

// ---------------- degree count + reciprocal ----------------
__global__ __launch_bounds__(256) void k_count(const int* __restrict__ dst, float* __restrict__ cnt) {
    int e = blockIdx.x * 256 + threadIdx.x;
    if (e < NE) atomicAdd(&cnt[dst[e]], 1.0f);
}

__global__ __launch_bounds__(256) void k_invcnt(float* __restrict__ cnt) {
    int i = blockIdx.x * 256 + threadIdx.x;
    if (i < NN) cnt[i] = 1.0f / fmaxf(cnt[i], 1.0f);
}

// ---------------- counting sort of edges by dst ----------------
__global__ __launch_bounds__(256) void k_hist(const int* __restrict__ dst, int* __restrict__ h) {
    int e = blockIdx.x * 256 + threadIdx.x;
    if (e < NE) atomicAdd(&h[dst[e]], 1);
}

__global__ __launch_bounds__(512) void k_scan1(const int* __restrict__ h,
                                               int* __restrict__ excl, int* __restrict__ bsum) {
    __shared__ int s[512];
    int tid = threadIdx.x;
    int i = blockIdx.x * 512 + tid;
    int v = (i < NN) ? h[i] : 0;
    s[tid] = v;
    __syncthreads();
    for (int off = 1; off < 512; off <<= 1) {
        int t = (tid >= off) ? s[tid - off] : 0;
        __syncthreads();
        s[tid] += t;
        __syncthreads();
    }
    if (i < NN) excl[i] = s[tid] - v;
    if (tid == 511) bsum[blockIdx.x] = s[511];
}

__global__ __launch_bounds__(128) void k_scan2(int* __restrict__ bsum, int nb) {
    __shared__ int s[128];
    int tid = threadIdx.x;
    int v = (tid < nb) ? bsum[tid] : 0;
    s[tid] = v;
    __syncthreads();
    for (int off = 1; off < 128; off <<= 1) {
        int t = (tid >= off) ? s[tid - off] : 0;
        __syncthreads();
        s[tid] += t;
        __syncthreads();
    }
    if (tid < nb) bsum[tid] = s[tid] - v;
}

__global__ __launch_bounds__(512) void k_scan3(const int* __restrict__ excl, const int* __restrict__ bsum,
                                               int* __restrict__ cursor) {
    int i = blockIdx.x * 512 + threadIdx.x;
    if (i < NN) cursor[i] = excl[i] + bsum[blockIdx.x];
}

__global__ __launch_bounds__(256) void k_scatter(const int* __restrict__ dst,
                                                 int* __restrict__ cursor, int* __restrict__ perm) {
    int e = blockIdx.x * 256 + threadIdx.x;
    if (e < NE) {
        int pos = atomicAdd(&cursor[dst[e]], 1);
        perm[pos] = e;
    }
}

__global__ __launch_bounds__(256) void k_permidx(const int* __restrict__ src, const int* __restrict__ dst,
                                                 const int* __restrict__ perm,
                                                 int* __restrict__ sp, int* __restrict__ dp) {
    int i = blockIdx.x * 256 + threadIdx.x;
    if (i < NE) {
        int pe = perm[i];
        sp[i] = src[pe];
        dp[i] = dst[pe];
    }
}

// ---------------- fp32 -> split bf16 planes ----------------
__global__ __launch_bounds__(256) void k_split(const float* __restrict__ in,
                                               u16* __restrict__ hi, u16* __restrict__ lo, int n) {
    int i = blockIdx.x * 256 + threadIdx.x;
    if (i < n) {
        float v = in[i];
        u16 h = f2bf(v);
        hi[i] = h;
        lo[i] = f2bf(v - bf2f(h));
    }
}

// permuted (dst-sorted) split of edge features: wave handles one row (64 cols)
__global__ __launch_bounds__(256) void k_split_e_perm(const float* __restrict__ e,
                                                      const int* __restrict__ perm,
                                                      u16* __restrict__ eh, u16* __restrict__ el) {
    int g = blockIdx.x * 256 + threadIdx.x;  // over NE*64
    int i = g >> 6, c = g & 63;
    if (i < NE) {
        float v = e[(long)perm[i] * 64 + c];
        u16 h = f2bf(v);
        eh[g] = h;
        el[g] = f2bf(v - bf2f(h));
    }
}

// ---------------- W[k][n] -> transposed split planes Wt[n][k] ----------------
__global__ __launch_bounds__(256) void k_wt(const float* __restrict__ W,
                                            u16* __restrict__ th, u16* __restrict__ tl,
                                            int K, int N) {
    int i = blockIdx.x * 256 + threadIdx.x;
    if (i < K * N) {
        int n = i / K, k = i - n * K;
        float v = W[(size_t)k * N + n];
        u16 h = f2bf(v);
        th[i] = h;
        tl[i] = f2bf(v - bf2f(h));
    }
}

// WeX^T: out[j][k] = We[k + (j>=64?128:0)][j&63], j,k in [0,128)
__global__ __launch_bounds__(256) void k_wt2(const float* __restrict__ We,
                                             u16* __restrict__ th, u16* __restrict__ tl) {
    int i = blockIdx.x * 256 + threadIdx.x;
    if (i < 128 * 128) {
        int j = i >> 7, k = i & 127;
        float v = We[(size_t)(k + ((j >> 6) << 7)) * 64 + (j & 63)];
        u16 h = f2bf(v);
        th[i] = h;
        tl[i] = f2bf(v - bf2f(h));
    }
}

// ================= generic node GEMM: C = x @ B + bias (fp32 out, no relu) =================
// rows=nodes (128/block), K=128 from x planes; B transposed planes with row stride bstride
__global__ __launch_bounds__(256) void k_ngemm(
    const u16* __restrict__ xh, const u16* __restrict__ xl,
    const u16* __restrict__ Bth, const u16* __restrict__ Btl, int bstride,
    const float* __restrict__ bias0, const float* __restrict__ bias1,  // cols 0-63 / 64-127
    float* __restrict__ C)
{
    __shared__ u16 Ah[128][40], Al[128][40], Bh[128][40], Bl[128][40];
    const int tid = threadIdx.x;
    const long rowbase = (long)blockIdx.x * 128;
    const int wave = tid >> 6, lane = tid & 63;
    const int quad = lane >> 4, lrow = lane & 15;
    const int wr = wave >> 1, wc = wave & 1;
    const int arow = tid >> 1, akh = (tid & 1) << 4;

    f32x4 acc[4][4];
#pragma unroll
    for (int r = 0; r < 4; ++r)
#pragma unroll
        for (int c = 0; c < 4; ++c) acc[r][c] = (f32x4){0.f, 0.f, 0.f, 0.f};

    for (int kp = 0; kp < 4; ++kp) {
        const int k0 = kp * 32;
        {
            long r = rowbase + arow; if (r >= NN) r = NN - 1;
            long b = r * 128 + k0 + akh;
            *(int4*)&Ah[arow][akh]     = *(const int4*)(xh + b);
            *(int4*)&Ah[arow][akh + 8] = *(const int4*)(xh + b + 8);
            *(int4*)&Al[arow][akh]     = *(const int4*)(xl + b);
            *(int4*)&Al[arow][akh + 8] = *(const int4*)(xl + b + 8);
        }
        {
            long b = (long)arow * bstride + k0 + akh;
            *(int4*)&Bh[arow][akh]     = *(const int4*)(Bth + b);
            *(int4*)&Bh[arow][akh + 8] = *(const int4*)(Bth + b + 8);
            *(int4*)&Bl[arow][akh]     = *(const int4*)(Btl + b);
            *(int4*)&Bl[arow][akh + 8] = *(const int4*)(Btl + b + 8);
        }
        __syncthreads();
        bf16x8 ah[4], al[4], bh[4], bl[4];
#pragma unroll
        for (int r = 0; r < 4; ++r) {
            ah[r] = *(const bf16x8*)&Ah[wr * 64 + r * 16 + lrow][quad * 8];
            al[r] = *(const bf16x8*)&Al[wr * 64 + r * 16 + lrow][quad * 8];
        }
#pragma unroll
        for (int c = 0; c < 4; ++c) {
            bh[c] = *(const bf16x8*)&Bh[wc * 64 + c * 16 + lrow][quad * 8];
            bl[c] = *(const bf16x8*)&Bl[wc * 64 + c * 16 + lrow][quad * 8];
        }
#pragma unroll
        for (int r = 0; r < 4; ++r)
#pragma unroll
            for (int c = 0; c < 4; ++c) {
                acc[r][c] = __builtin_amdgcn_mfma_f32_16x16x32_bf16(ah[r], bh[c], acc[r][c], 0, 0, 0);
                acc[r][c] = __builtin_amdgcn_mfma_f32_16x16x32_bf16(ah[r], bl[c], acc[r][c], 0, 0, 0);
                acc[r][c] = __builtin_amdgcn_mfma_f32_16x16x32_bf16(al[r], bh[c], acc[r][c], 0, 0, 0);
            }
        __syncthreads();
    }
#pragma unroll
    for (int c = 0; c < 4; ++c) {
        int colg = wc * 64 + c * 16 + lrow;
        float bv = (colg < 64) ? bias0[colg] : bias1[colg - 64];
#pragma unroll
        for (int r = 0; r < 4; ++r)
#pragma unroll
            for (int j = 0; j < 4; ++j) {
                long grow = rowbase + wr * 64 + r * 16 + quad * 4 + j;
                if (grow < NN) C[grow * 128 + colg] = acc[r][c][j] + bv;
            }
    }
}

// ================= message kernel: m = relu(y[src] + e@Wme); run-scan aggregate =================
// edges physically dst-sorted; A-frags direct from global (sequential); B LDS-resident (K=64)
__global__ __launch_bounds__(256) void k_msg2(
    const u16* __restrict__ eh, const u16* __restrict__ el,
    const int* __restrict__ sp, const int* __restrict__ dp,
    const u16* __restrict__ Bth, const u16* __restrict__ Btl,  // layer Wmt base [128][192]; use k=128..191
    const float* __restrict__ y,
    float* __restrict__ agg)
{
    __shared__ union {
        struct { u16 Bh[128][72]; u16 Bl[128][72]; } b;  // 36864 B
        float cbuf[128][66];                              // 33792 B
    } u;
    __shared__ int s_sp[128], s_dp[128];
    const int tid = threadIdx.x;
    const long rowbase = (long)blockIdx.x * 128;
    if (tid < 128) {
        long r = rowbase + tid;
        if (r < NE) { s_sp[tid] = sp[r]; s_dp[tid] = dp[r]; }
        else        { s_sp[tid] = 0;     s_dp[tid] = -1;    }
    }
    // stage B (whole K=64) once
    {
        int colb = tid >> 1, kh = (tid & 1) * 32;
        long bb = (long)colb * 192 + 128 + kh;
#pragma unroll
        for (int q = 0; q < 32; q += 8) {
            *(int4*)&u.b.Bh[colb][kh + q] = *(const int4*)(Bth + bb + q);
            *(int4*)&u.b.Bl[colb][kh + q] = *(const int4*)(Btl + bb + q);
        }
    }
    __syncthreads();
    const int wave = tid >> 6, lane = tid & 63;
    const int quad = lane >> 4, lrow = lane & 15;
    const int wr = wave >> 1, wc = wave & 1;

    f32x4 acc[4][4];
#pragma unroll
    for (int r = 0; r < 4; ++r)
#pragma unroll
        for (int c = 0; c < 4; ++c) acc[r][c] = (f32x4){0.f, 0.f, 0.f, 0.f};

#pragma unroll
    for (int kp = 0; kp < 2; ++kp) {
        bf16x8 ah[4], al[4], bh[4], bl[4];
#pragma unroll
        for (int r = 0; r < 4; ++r) {
            long row = rowbase + wr * 64 + r * 16 + lrow; if (row >= NE) row = NE - 1;
            long ba = row * 64 + kp * 32 + quad * 8;
            ah[r] = *(const bf16x8*)(eh + ba);
            al[r] = *(const bf16x8*)(el + ba);
        }
#pragma unroll
        for (int c = 0; c < 4; ++c) {
            bh[c] = *(const bf16x8*)&u.b.Bh[wc * 64 + c * 16 + lrow][kp * 32 + quad * 8];
            bl[c] = *(const bf16x8*)&u.b.Bl[wc * 64 + c * 16 + lrow][kp * 32 + quad * 8];
        }
#pragma unroll
        for (int r = 0; r < 4; ++r)
#pragma unroll
            for (int c = 0; c < 4; ++c) {
                acc[r][c] = __builtin_amdgcn_mfma_f32_16x16x32_bf16(ah[r], bh[c], acc[r][c], 0, 0, 0);
                acc[r][c] = __builtin_amdgcn_mfma_f32_16x16x32_bf16(ah[r], bl[c], acc[r][c], 0, 0, 0);
                acc[r][c] = __builtin_amdgcn_mfma_f32_16x16x32_bf16(al[r], bh[c], acc[r][c], 0, 0, 0);
            }
    }
    __syncthreads();   // B region now reusable as cbuf
    // epilogue: add gathered y, relu, run-scan over dst-runs, coalesced atomic flush
    const int col = tid & 63, seg = tid >> 6;
    for (int p = 0; p < 2; ++p) {
        if (wc == p) {
#pragma unroll
            for (int c = 0; c < 4; ++c) {
                int colg = p * 64 + c * 16 + lrow;
#pragma unroll
                for (int r = 0; r < 4; ++r)
#pragma unroll
                    for (int j = 0; j < 4; ++j) {
                        int lrw = wr * 64 + r * 16 + quad * 4 + j;
                        float yv = y[(long)s_sp[lrw] * 128 + colg];
                        u.cbuf[lrw][c * 16 + lrow] = relu_f(acc[r][c][j] + yv);
                    }
            }
        }
        __syncthreads();
        int cur = -1; float sum = 0.0f;
        for (int rr = seg * 32; rr < seg * 32 + 32; ++rr) {
            int d = s_dp[rr];
            if (d != cur) {
                if (cur >= 0) atomicAdd(&agg[(long)cur * 128 + p * 64 + col], sum);
                cur = d; sum = 0.0f;
            }
            sum += u.cbuf[rr][col];
        }
        if (cur >= 0) atomicAdd(&agg[(long)cur * 128 + p * 64 + col], sum);
        __syncthreads();
    }
}

// ================= node update GEMM (MFMA, split bf16, fused L2-norm) =================
__global__ __launch_bounds__(256) void k_update_mfma(
    const float* __restrict__ agg, const float* __restrict__ icnt,
    u16* __restrict__ xh, u16* __restrict__ xl,
    const u16* __restrict__ Bth, const u16* __restrict__ Btl,   // [128][256]
    const float* __restrict__ bias)
{
    __shared__ u16 Ah[128][40], Al[128][40], Bh[128][40], Bl[128][40];
    __shared__ float s_ic[128];
    __shared__ float sP[128][2];
    const int tid = threadIdx.x;
    const long rowbase = (long)blockIdx.x * 128;
    if (tid < 128) {
        long r = rowbase + tid;
        int rr = (r < NN) ? (int)r : (NN - 1);
        s_ic[tid] = icnt[rr];
    }
    __syncthreads();
    const int wave = tid >> 6, lane = tid & 63;
    const int quad = lane >> 4, lrow = lane & 15;
    const int wr = wave >> 1, wc = wave & 1;
    const int arow = tid >> 1, akh = (tid & 1) << 4;

    f32x4 acc[4][4];
#pragma unroll
    for (int r = 0; r < 4; ++r)
#pragma unroll
        for (int c = 0; c < 4; ++c) acc[r][c] = (f32x4){0.f, 0.f, 0.f, 0.f};

    for (int kp = 0; kp < 8; ++kp) {
        const int k0 = kp * 32;
        if (k0 < 128) {
            long r = rowbase + arow; if (r >= NN) r = NN - 1;
            const float* pa = agg + r * 128 + k0 + akh;
            float ic = s_ic[arow];
#pragma unroll
            for (int q = 0; q < 16; q += 4) {
                float4 f = *(const float4*)(pa + q);
                float vv[4] = {f.x, f.y, f.z, f.w};
#pragma unroll
                for (int j = 0; j < 4; ++j) {
                    float v = vv[j] * ic;
                    u16 h = f2bf(v);
                    Ah[arow][akh + q + j] = h;
                    Al[arow][akh + q + j] = f2bf(v - bf2f(h));
                }
            }
        } else {
            long r = rowbase + arow; if (r >= NN) r = NN - 1;
            long b = r * 128 + (k0 - 128 + akh);
            *(int4*)&Ah[arow][akh]     = *(const int4*)(xh + b);
            *(int4*)&Ah[arow][akh + 8] = *(const int4*)(xh + b + 8);
            *(int4*)&Al[arow][akh]     = *(const int4*)(xl + b);
            *(int4*)&Al[arow][akh + 8] = *(const int4*)(xl + b + 8);
        }
        {
            long b = (long)arow * 256 + k0 + akh;
            *(int4*)&Bh[arow][akh]     = *(const int4*)(Bth + b);
            *(int4*)&Bh[arow][akh + 8] = *(const int4*)(Bth + b + 8);
            *(int4*)&Bl[arow][akh]     = *(const int4*)(Btl + b);
            *(int4*)&Bl[arow][akh + 8] = *(const int4*)(Btl + b + 8);
        }
        __syncthreads();
        bf16x8 ah[4], al[4], bh[4], bl[4];
#pragma unroll
        for (int r = 0; r < 4; ++r) {
            ah[r] = *(const bf16x8*)&Ah[wr * 64 + r * 16 + lrow][quad * 8];
            al[r] = *(const bf16x8*)&Al[wr * 64 + r * 16 + lrow][quad * 8];
        }
#pragma unroll
        for (int c = 0; c < 4; ++c) {
            bh[c] = *(const bf16x8*)&Bh[wc * 64 + c * 16 + lrow][quad * 8];
            bl[c] = *(const bf16x8*)&Bl[wc * 64 + c * 16 + lrow][quad * 8];
        }
#pragma unroll
        for (int r = 0; r < 4; ++r)
#pragma unroll
            for (int c = 0; c < 4; ++c) {
                acc[r][c] = __builtin_amdgcn_mfma_f32_16x16x32_bf16(ah[r], bh[c], acc[r][c], 0, 0, 0);
                acc[r][c] = __builtin_amdgcn_mfma_f32_16x16x32_bf16(ah[r], bl[c], acc[r][c], 0, 0, 0);
                acc[r][c] = __builtin_amdgcn_mfma_f32_16x16x32_bf16(al[r], bh[c], acc[r][c], 0, 0, 0);
            }
        __syncthreads();
    }
#pragma unroll
    for (int r = 0; r < 4; ++r)
#pragma unroll
        for (int c = 0; c < 4; ++c)
#pragma unroll
            for (int j = 0; j < 4; ++j)
                acc[r][c][j] = relu_f(acc[r][c][j] + bias[wc * 64 + c * 16 + lrow]);
#pragma unroll
    for (int r = 0; r < 4; ++r)
#pragma unroll
        for (int j = 0; j < 4; ++j) {
            float s2 = 0.0f;
#pragma unroll
            for (int c = 0; c < 4; ++c) { float v = acc[r][c][j]; s2 += v * v; }
#pragma unroll
            for (int m = 1; m < 16; m <<= 1) s2 += __shfl_xor(s2, m, 64);
            if (lrow == 0) sP[wr * 64 + r * 16 + quad * 4 + j][wc] = s2;
        }
    __syncthreads();
#pragma unroll
    for (int r = 0; r < 4; ++r)
#pragma unroll
        for (int j = 0; j < 4; ++j) {
            int lr = wr * 64 + r * 16 + quad * 4 + j;
            long grow = rowbase + lr;
            if (grow < NN) {
                float tot = sP[lr][0] + sP[lr][1];
                float rn = 1.0f / fmaxf(sqrtf(tot), 1e-12f);
#pragma unroll
                for (int c = 0; c < 4; ++c) {
                    float v = acc[r][c][j] * rn;
                    long o = grow * 128 + wc * 64 + c * 16 + lrow;
                    u16 h = f2bf(v);
                    xh[o] = h;
                    xl[o] = f2bf(v - bf2f(h));
                }
            }
        }
}

// ================= edge update: e' = relu(u1[src] + u2[dst] + e@We3) =================
// edges dst-sorted; A-frags direct global; B (We3, 64x64) LDS-resident; in-place split write
__global__ __launch_bounds__(256) void k_edge2(
    u16* __restrict__ eh, u16* __restrict__ el,
    const int* __restrict__ sp, const int* __restrict__ dp,
    const u16* __restrict__ Bth, const u16* __restrict__ Btl,  // Wet layer [64][320]; use k=256..319
    const float* __restrict__ uu)                              // [NN][128] = [u1|u2]
{
    __shared__ u16 Bh[64][72], Bl[64][72];
    __shared__ int s_sp[256], s_dp[256];
    const int tid = threadIdx.x;
    const long rowbase = (long)blockIdx.x * 256;
    {
        long r = rowbase + tid;
        int rr = (r < NE) ? (int)r : (NE - 1);
        s_sp[tid] = sp[rr];
        s_dp[tid] = dp[rr];
    }
    {
        int colb = tid >> 2, kh = (tid & 3) * 16;
        long bb = (long)colb * 320 + 256 + kh;
        *(int4*)&Bh[colb][kh]     = *(const int4*)(Bth + bb);
        *(int4*)&Bh[colb][kh + 8] = *(const int4*)(Bth + bb + 8);
        *(int4*)&Bl[colb][kh]     = *(const int4*)(Btl + bb);
        *(int4*)&Bl[colb][kh + 8] = *(const int4*)(Btl + bb + 8);
    }
    __syncthreads();
    const int wave = tid >> 6, lane = tid & 63;
    const int quad = lane >> 4, lrow = lane & 15;

    f32x4 acc[4][4];
#pragma unroll
    for (int r = 0; r < 4; ++r)
#pragma unroll
        for (int c = 0; c < 4; ++c) acc[r][c] = (f32x4){0.f, 0.f, 0.f, 0.f};

#pragma unroll
    for (int kp = 0; kp < 2; ++kp) {
        bf16x8 ah[4], al[4], bh[4], bl[4];
#pragma unroll
        for (int r = 0; r < 4; ++r) {
            long row = rowbase + wave * 64 + r * 16 + lrow; if (row >= NE) row = NE - 1;
            long ba = row * 64 + kp * 32 + quad * 8;
            ah[r] = *(const bf16x8*)(eh + ba);
            al[r] = *(const bf16x8*)(el + ba);
        }
#pragma unroll
        for (int c = 0; c < 4; ++c) {
            bh[c] = *(const bf16x8*)&Bh[c * 16 + lrow][kp * 32 + quad * 8];
            bl[c] = *(const bf16x8*)&Bl[c * 16 + lrow][kp * 32 + quad * 8];
        }
#pragma unroll
        for (int r = 0; r < 4; ++r)
#pragma unroll
            for (int c = 0; c < 4; ++c) {
                acc[r][c] = __builtin_amdgcn_mfma_f32_16x16x32_bf16(ah[r], bh[c], acc[r][c], 0, 0, 0);
                acc[r][c] = __builtin_amdgcn_mfma_f32_16x16x32_bf16(ah[r], bl[c], acc[r][c], 0, 0, 0);
                acc[r][c] = __builtin_amdgcn_mfma_f32_16x16x32_bf16(al[r], bh[c], acc[r][c], 0, 0, 0);
            }
    }
#pragma unroll
    for (int c = 0; c < 4; ++c) {
        int colg = c * 16 + lrow;
#pragma unroll
        for (int r = 0; r < 4; ++r)
#pragma unroll
            for (int j = 0; j < 4; ++j) {
                int lrw = wave * 64 + r * 16 + quad * 4 + j;
                long grow = rowbase + lrw;
                if (grow < NE) {
                    float v = relu_f(acc[r][c][j]
                        + uu[(long)s_sp[lrw] * 128 + colg]
                        + uu[(long)s_dp[lrw] * 128 + 64 + colg]);
                    long o = grow * 64 + colg;
                    u16 h = f2bf(v);
                    eh[o] = h;
                    el[o] = f2bf(v - bf2f(h));
                }
            }
    }
}

// ---------------- MLP head, layer 1: 128 -> 64, relu ----------------
__global__ __launch_bounds__(256) void k_head1(
    const u16* __restrict__ xh, const u16* __restrict__ xl,
    const float* __restrict__ W, const float* __restrict__ bias,
    float* __restrict__ h)
{
    constexpr int KC = 64, NP = 2, EB = 32;
    __shared__ __align__(16) float At[KC][EB + 4];
    __shared__ __align__(16) float Wc[KC][64];
    const int tid = threadIdx.x;
    const int rowbase = blockIdx.x * EB;
    const int wave = tid >> 6, lane = tid & 63;
    float acc[8];
#pragma unroll
    for (int i = 0; i < 8; ++i) acc[i] = 0.0f;

    for (int kp = 0; kp < NP; ++kp) {
        const int k0 = kp * KC;
        for (int i = tid; i < KC * EB; i += 256) {
            int e = i >> 6, kk = i & 63, k = k0 + kk;
            int r = min(rowbase + e, NN - 1);
            long b = (long)r * 128 + k;
            At[kk][e] = bf2f(xh[b]) + bf2f(xl[b]);
        }
        for (int i = tid; i < KC * 64; i += 256) {
            int kk = i >> 6, cc = i & 63;
            Wc[kk][cc] = W[(size_t)(k0 + kk) * 64 + cc];
        }
        __syncthreads();
#pragma unroll 4
        for (int kk = 0; kk < KC; ++kk) {
            const float* ar = &At[kk][wave * 8];
            float4 a0 = *(const float4*)ar;
            float4 a1 = *(const float4*)(ar + 4);
            float wv = Wc[kk][lane];
            acc[0] += a0.x * wv; acc[1] += a0.y * wv; acc[2] += a0.z * wv; acc[3] += a0.w * wv;
            acc[4] += a1.x * wv; acc[5] += a1.y * wv; acc[6] += a1.z * wv; acc[7] += a1.w * wv;
        }
        __syncthreads();
    }
    const float bv = bias[lane];
#pragma unroll
    for (int j = 0; j < 8; ++j) {
        int r = rowbase + wave * 8 + j;
        if (r < NN) h[(size_t)r * 64 + lane] = relu_f(acc[j] + bv);
    }
}

// ---------------- MLP head, layer 2: 64 -> 128, no relu ----------------
__global__ __launch_bounds__(256) void k_head2(
    const float* __restrict__ h, const float* __restrict__ W, const float* __restrict__ bias,
    float* __restrict__ out)
{
    constexpr int KC = 64, EB = 32;
    __shared__ __align__(16) float At[KC][EB + 4];
    __shared__ __align__(16) float Wc[KC][128];
    const int tid = threadIdx.x;
    const int rowbase = blockIdx.x * EB;
    const int wave = tid >> 6, lane = tid & 63;
    float acc[16];
#pragma unroll
    for (int i = 0; i < 16; ++i) acc[i] = 0.0f;

    for (int i = tid; i < KC * EB; i += 256) {
        int e = i >> 6, kk = i & 63;
        int r = min(rowbase + e, NN - 1);
        At[kk][e] = h[(size_t)r * 64 + kk];
    }
    for (int i = tid; i < KC * 128; i += 256) {
        int kk = i >> 7, cc = i & 127;
        Wc[kk][cc] = W[(size_t)kk * 128 + cc];
    }
    __syncthreads();
#pragma unroll 4
    for (int kk = 0; kk < KC; ++kk) {
        const float* ar = &At[kk][wave * 8];
        float4 a0 = *(const float4*)ar;
        float4 a1 = *(const float4*)(ar + 4);
        float w0 = Wc[kk][lane], w1 = Wc[kk][64 + lane];
        acc[0] += a0.x * w0;  acc[1] += a0.y * w0;  acc[2] += a0.z * w0;  acc[3] += a0.w * w0;
        acc[4] += a1.x * w0;  acc[5] += a1.y * w0;  acc[6] += a1.z * w0;  acc[7] += a1.w * w0;
        acc[8] += a0.x * w1;  acc[9] += a0.y * w1;  acc[10] += a0.z * w1; acc[11] += a0.w * w1;
        acc[12] += a1.x * w1; acc[13] += a1.y * w1; acc[14] += a1.z * w1; acc[15] += a1.w * w1;
    }
    const float b0 = bias[lane], b1 = bias[64 + lane];
#pragma unroll
    for (int j = 0; j < 8; ++j) {
        int r = rowbase + wave * 8 + j;
        if (r < NN) {
            out[(size_t)r * 128 + lane] = acc[j] + b0;
            out[(size_t)r * 128 + 64 + lane] = acc[8 + j] + b1;
        }
    }
}

// ---------------- host-side launch ----------------
extern "C" void kernel_launch(void* const* d_in, const int* in_sizes, int n_in,
                              void* d_out, int out_size, void* d_ws, size_t ws_size,
                              hipStream_t stream) {
    const float* d_x  = (const float*)d_in[0];
    const float* d_ea = (const float*)d_in[1];
    const int*   d_ei = (const int*)d_in[2];
    const float* Wm   = (const float*)d_in[3];
    const float* bm   = (const float*)d_in[4];
    const float* Wa   = (const float*)d_in[5];
    const float* ba   = (const float*)d_in[6];
    const float* We   = (const float*)d_in[7];
    const float* be   = (const float*)d_in[8];
    const float* W1   = (const float*)d_in[9];
    const float* b1   = (const float*)d_in[10];
    const float* W2   = (const float*)d_in[11];
    const float* b2   = (const float*)d_in[12];
    float* out = (float*)d_out;

    const int* src = d_ei;
    const int* dst = d_ei + NE;

    char* p = (char*)d_ws;
    auto alloc = [&](size_t bytes) { char* q = p; p += (bytes + 255) & ~(size_t)255; return q; };
    u16* xh  = (u16*)alloc((size_t)NN * 128 * 2);
    u16* xl  = (u16*)alloc((size_t)NN * 128 * 2);
    u16* ehb = (u16*)alloc((size_t)NE * 64 * 2);
    u16* elb = (u16*)alloc((size_t)NE * 64 * 2);
    float* agg = (float*)alloc((size_t)NN * 128 * 4);
    float* yu  = (float*)alloc((size_t)NN * 128 * 4);   // y, then u (disjoint lifetimes)
    float* cnt = (float*)alloc((size_t)NN * 4);
    float* zbuf = (float*)alloc(64 * 4);
    u16* Wmt_h = (u16*)alloc((size_t)3 * 192 * 128 * 2);
    u16* Wmt_l = (u16*)alloc((size_t)3 * 192 * 128 * 2);
    u16* Wat_h = (u16*)alloc((size_t)3 * 256 * 128 * 2);
    u16* Wat_l = (u16*)alloc((size_t)3 * 256 * 128 * 2);
    u16* Wet_h = (u16*)alloc((size_t)3 * 320 * 64 * 2);
    u16* Wet_l = (u16*)alloc((size_t)3 * 320 * 64 * 2);
    u16* Wxt_h = (u16*)alloc((size_t)3 * 128 * 128 * 2);
    u16* Wxt_l = (u16*)alloc((size_t)3 * 128 * 128 * 2);
    int* hist   = (int*)alloc((size_t)NN * 4);
    int* excl   = (int*)alloc((size_t)NN * 4);
    int* bsum   = (int*)alloc(128 * 4);
    int* cursor = (int*)alloc((size_t)NN * 4);
    int* perm   = (int*)alloc((size_t)NE * 4);
    int* sp     = (int*)alloc((size_t)NE * 4);
    int* dp     = (int*)alloc((size_t)NE * 4);
    float* hbuf = yu;   // alias: yu free after last k_edge2

    const int NB1 = (NN + 511) / 512;

    hipMemsetAsync(cnt, 0, NN * sizeof(float), stream);
    hipMemsetAsync(hist, 0, NN * sizeof(int), stream);
    hipMemsetAsync(zbuf, 0, 64 * sizeof(float), stream);
    k_count<<<(NE + 255) / 256, 256, 0, stream>>>(dst, cnt);
    k_invcnt<<<(NN + 255) / 256, 256, 0, stream>>>(cnt);

    // counting sort by dst; physical permutation of edge data
    k_hist<<<(NE + 255) / 256, 256, 0, stream>>>(dst, hist);
    k_scan1<<<NB1, 512, 0, stream>>>(hist, excl, bsum);
    k_scan2<<<1, 128, 0, stream>>>(bsum, NB1);
    k_scan3<<<NB1, 512, 0, stream>>>(excl, bsum, cursor);
    k_scatter<<<(NE + 255) / 256, 256, 0, stream>>>(dst, cursor, perm);
    k_permidx<<<(NE + 255) / 256, 256, 0, stream>>>(src, dst, perm, sp, dp);

    k_split<<<(NN * 128 + 255) / 256, 256, 0, stream>>>(d_x, xh, xl, NN * 128);
    k_split_e_perm<<<(NE * 64 + 255) / 256, 256, 0, stream>>>(d_ea, perm, ehb, elb);
    for (int l = 0; l < 3; ++l) {
        k_wt<<<(192 * 128 + 255) / 256, 256, 0, stream>>>(Wm + (size_t)l * 192 * 128,
            Wmt_h + (size_t)l * 192 * 128, Wmt_l + (size_t)l * 192 * 128, 192, 128);
        k_wt<<<(256 * 128 + 255) / 256, 256, 0, stream>>>(Wa + (size_t)l * 256 * 128,
            Wat_h + (size_t)l * 256 * 128, Wat_l + (size_t)l * 256 * 128, 256, 128);
        k_wt<<<(320 * 64 + 255) / 256, 256, 0, stream>>>(We + (size_t)l * 320 * 64,
            Wet_h + (size_t)l * 320 * 64, Wet_l + (size_t)l * 320 * 64, 320, 64);
        k_wt2<<<(128 * 128 + 255) / 256, 256, 0, stream>>>(We + (size_t)l * 320 * 64,
            Wxt_h + (size_t)l * 128 * 128, Wxt_l + (size_t)l * 128 * 128);
    }

    const int NGB = (NN + 127) / 128;
    for (int l = 0; l < 3; ++l) {
        // y = x @ Wm[0:128] + bm   (node-level hoist of message GEMM)
        k_ngemm<<<NGB, 256, 0, stream>>>(xh, xl,
            Wmt_h + (size_t)l * 192 * 128, Wmt_l + (size_t)l * 192 * 128, 192,
            bm + (size_t)l * 128, bm + (size_t)l * 128 + 64, yu);
        hipMemsetAsync(agg, 0, (size_t)NN * 128 * sizeof(float), stream);
        k_msg2<<<(NE + 127) / 128, 256, 0, stream>>>(
            ehb, elb, sp, dp,
            Wmt_h + (size_t)l * 192 * 128, Wmt_l + (size_t)l * 192 * 128,
            yu, agg);
        k_update_mfma<<<NGB, 256, 0, stream>>>(
            agg, cnt, xh, xl,
            Wat_h + (size_t)l * 256 * 128, Wat_l + (size_t)l * 256 * 128,
            ba + (size_t)l * 128);
        // u = x_new @ [We1|We2] (+be on u1 half)   (node-level hoist of edge GEMM)
        k_ngemm<<<NGB, 256, 0, stream>>>(xh, xl,
            Wxt_h + (size_t)l * 128 * 128, Wxt_l + (size_t)l * 128 * 128, 128,
            be + (size_t)l * 64, zbuf, yu);
        k_edge2<<<(NE + 255) / 256, 256, 0, stream>>>(
            ehb, elb, sp, dp,
            Wet_h + (size_t)l * 320 * 64, Wet_l + (size_t)l * 320 * 64,
            yu);
    }
    k_head1<<<(NN + 31) / 32, 256, 0, stream>>>(xh, xl, W1, b1, hbuf);
    k_head2<<<(NN + 31) / 32, 256, 0, stream>>>(hbuf, W2, b2, out);
}